// Round 5
// baseline (644.733 us; speedup 1.0000x reference)
//
#include <hip/hip_runtime.h>

// FWLNet pipeline; see R5-R16 notes.
//
// R16 (from R15 CORRECTNESS FAIL, absmax 2.09): single bug — prodgemm
// C-writeback loop iterated it<8 (cu up to 504) on a 256-col tile: read
// LDS garbage past the staging region AND stored OOB into neighboring
// tiles (j0+cu up to 1272). Fix: it<4 (cu 0..255; 512thr x 4 x 16B =
// 64rows x 256cols). Everything else identical to R15:
//  - k_buildT: R12 version (66us known-good).
//  - k_prodgemm: 256^2/BK=64/8-wave counted-vmcnt schedule, 1 block/CU,
//    128KB LDS dbuf, stage tile kt+1 at top of tile kt, vmcnt(8), 4
//    setprio-wrapped MFMA phases/tile, T2 swizzle (pre-swizzled source +
//    XOR read).
//
// ws layout unchanged (~194.4 MB).

typedef unsigned short u16;
typedef unsigned int u32;

#define DI static __device__ __forceinline__

DI float bf2f(u16 u) { union { u32 i; float f; } v; v.i = ((u32)u) << 16; return v.f; }
DI u16 f2bf(float f) {
  union { float f; u32 i; } v; v.f = f;
  u32 u = v.i;
  return (u16)((u + 0x7fffu + ((u >> 16) & 1u)) >> 16);
}

typedef __bf16 bf16x8 __attribute__((ext_vector_type(8)));
typedef float f32x4 __attribute__((ext_vector_type(4)));

#define MFMA16(a, b, c) __builtin_amdgcn_mfma_f32_16x16x32_bf16((a), (b), (c), 0, 0, 0)

typedef const __attribute__((address_space(1))) u32* gas1;
typedef __attribute__((address_space(3))) u32* las3;

// ---------------- node pipeline ----------------

__global__ void k_setup(const int* __restrict__ xids, const float* __restrict__ emb,
                        float* __restrict__ xf, float* __restrict__ deg,
                        u32* __restrict__ eimu) {
  int g = blockIdx.x * 256 + threadIdx.x;  // grid 1024
  if (g < 262144) eimu[g] = 0u;
  if (g < 1024) deg[g] = 1.0f;  // self-loop
  if (g < 65536) {
    int i = g >> 6, d = g & 63;
    xf[g] = emb[xids[i] * 64 + d];
  }
}

__global__ void k_edges(const int* __restrict__ ei, float* __restrict__ deg,
                        unsigned char* __restrict__ eim) {
  int e = blockIdx.x * 256 + threadIdx.x;  // grid 64
  if (e < 16384) {
    int s = ei[e], d = ei[16384 + e];
    atomicAdd(&deg[d], 1.0f);
    eim[s * 1024 + d] = 1;
  }
}

__global__ void k_gemm_node(const float* __restrict__ xf, const float* __restrict__ W,
                            const float* __restrict__ gb, const float* __restrict__ deg,
                            float* __restrict__ h, float* __restrict__ agg) {
  __shared__ float xrow[64];
  int i = blockIdx.x, c = threadIdx.x;  // grid 1024 x 64
  xrow[c] = xf[i * 64 + c];
  __syncthreads();
  float s = 0.f;
#pragma unroll
  for (int d = 0; d < 64; ++d) s += xrow[d] * W[d * 64 + c];
  h[i * 64 + c] = s;
  agg[i * 64 + c] = s / deg[i] + gb[c];
}

__global__ void k_agg(const int* __restrict__ ei, const float* __restrict__ deg,
                      const float* __restrict__ h, float* __restrict__ agg) {
  int g = blockIdx.x * 256 + threadIdx.x;  // grid 4096 -> e x c
  int e = g >> 6, c = g & 63;
  int s = ei[e], d = ei[16384 + e];
  float nrm = rsqrtf(deg[s]) * rsqrtf(deg[d]);
  atomicAdd(&agg[d * 64 + c], nrm * h[s * 64 + c]);
}

__global__ void k_gnorm(const float* __restrict__ agg, const float* __restrict__ gw,
                        const float* __restrict__ gbb, const float* __restrict__ ga,
                        float* __restrict__ xf, u16* __restrict__ xb, int last) {
  int c = blockIdx.x, t = threadIdx.x;  // grid 64 x 256
  float s = 0.f, ss = 0.f;
  for (int i = t; i < 1024; i += 256) {
    float v = agg[i * 64 + c];
    s += v; ss += v * v;
  }
  __shared__ float Ls[256], Lss[256];
  Ls[t] = s; Lss[t] = ss;
  __syncthreads();
  for (int off = 128; off > 0; off >>= 1) {
    if (t < off) { Ls[t] += Ls[t + off]; Lss[t] += Lss[t + off]; }
    __syncthreads();
  }
  float m = Ls[0] * (1.f / 1024.f);
  float a = ga[c];
  float var = Lss[0] * (1.f / 1024.f) - (2.f * a - a * a) * m * m;
  float sc = gw[c] * rsqrtf(fmaxf(var, 0.f) + 1e-5f);
  float bb = gbb[c];
  for (int i = t; i < 1024; i += 256) {
    float v = agg[i * 64 + c];
    float y = fmaxf(sc * (v - a * m) + bb, 0.f);
    xf[i * 64 + c] = y;
    if (last) xb[i * 64 + c] = f2bf(y);
  }
}

// ---------------- x1t / x2T builder: 4 channels per block ----------------
__global__ __launch_bounds__(256, 2) void k_build12(
    const u16* __restrict__ xbg, const unsigned char* __restrict__ eim,
    const float* __restrict__ m1W, const float* __restrict__ m1b,
    const float* __restrict__ m2W, const float* __restrict__ m2b,
    u16* __restrict__ x1tg, u16* __restrict__ x2tg, int cbase) {
  __shared__ u16 As[128 * 80];
  __shared__ u16 Bs[128 * 80];
  __shared__ u16 Cs[64 * 140];
  __shared__ unsigned char El[128 * 132];
  __shared__ float wsc[64];
  int b = blockIdx.x;  // grid 512 = 2(which) x 64 tiles x 4 channel-quads
  int cg = b & 3;
  int rest = b >> 2;
  int which = rest >> 6;
  int t6 = rest & 63;
  int rbase = (t6 >> 3) * 128, sbase = (t6 & 7) * 128;
  const float* W = which ? m2W : m1W;
  const float* bias = which ? m2b : m1b;
  u16* outg = which ? x2tg : x1tg;
  int t = threadIdx.x;
  {
    int row = t >> 1, half = t & 1;
    const u32* gB = (const u32*)(xbg + (sbase + row) * 64 + half * 32);
    u32* dstB = (u32*)&Bs[row * 80 + half * 32];
#pragma unroll
    for (int k = 0; k < 16; ++k) dstB[k] = gB[k];
    int ab = which ? sbase : rbase;
    int bb = which ? rbase : sbase;
    const u32* gE = (const u32*)(eim + (size_t)(ab + row) * 1024 + bb + half * 64);
    u32* dstE = (u32*)&El[row * 132 + half * 64];
#pragma unroll
    for (int k = 0; k < 16; ++k) dstE[k] = gE[k];
  }
  int lane = t & 63, w = t >> 6;
  int q = lane >> 4, r = lane & 15;
  int wr = w >> 1, wc = w & 1;
  for (int ci = 0; ci < 4; ++ci) {
    int cl = cg * 4 + ci;
    int c = cbase + cl;
    if (t < 64) wsc[t] = W[t * 64 + c];
    __syncthreads();
    {
      int row = t >> 1, half = t & 1;
      const u32* ga = (const u32*)(xbg + (rbase + row) * 64 + half * 32);
      u32* dstA = (u32*)&As[row * 80 + half * 32];
#pragma unroll
      for (int k = 0; k < 16; ++k) {
        u32 u = ga[k];
        float f0 = bf2f((u16)(u & 0xffffu)) * wsc[half * 32 + 2 * k];
        float f1 = bf2f((u16)(u >> 16)) * wsc[half * 32 + 2 * k + 1];
        dstA[k] = (u32)f2bf(f0) | ((u32)f2bf(f1) << 16);
      }
    }
    __syncthreads();
    f32x4 z4 = {0.f, 0.f, 0.f, 0.f};
    f32x4 acc[4][4];
#pragma unroll
    for (int mi = 0; mi < 4; ++mi)
#pragma unroll
      for (int ni = 0; ni < 4; ++ni) acc[mi][ni] = z4;
#pragma unroll
    for (int ks = 0; ks < 2; ++ks) {
      bf16x8 af[4], bfr[4];
#pragma unroll
      for (int mi = 0; mi < 4; ++mi)
        af[mi] = *(const bf16x8*)&As[(wr * 64 + mi * 16 + r) * 80 + ks * 32 + q * 8];
#pragma unroll
      for (int ni = 0; ni < 4; ++ni)
        bfr[ni] = *(const bf16x8*)&Bs[(wc * 64 + ni * 16 + r) * 80 + ks * 32 + q * 8];
#pragma unroll
      for (int mi = 0; mi < 4; ++mi)
#pragma unroll
        for (int ni = 0; ni < 4; ++ni) acc[mi][ni] = MFMA16(af[mi], bfr[ni], acc[mi][ni]);
    }
    float w64 = W[64 * 64 + c];
    float bsv = bias[c];
#pragma unroll
    for (int mi = 0; mi < 4; ++mi) {
#pragma unroll
      for (int ni = 0; ni < 4; ++ni) {
        int col = wc * 64 + ni * 16 + r;
#pragma unroll
        for (int tt = 0; tt < 4; ++tt) {
          int row2 = wr * 64 + mi * 16 + q * 4 + tt;
          float e = (float)(which ? El[col * 132 + row2] : El[row2 * 132 + col]);
          acc[mi][ni][tt] = fmaxf(acc[mi][ni][tt] + e * w64 + bsv, 0.f);
        }
      }
    }
    u16* outp = outg + (size_t)cl * 1048576;
#pragma unroll
    for (int p = 0; p < 2; ++p) {
      __syncthreads();
      if (wr == p) {
#pragma unroll
        for (int mi = 0; mi < 4; ++mi)
#pragma unroll
          for (int ni = 0; ni < 4; ++ni) {
            int col = wc * 64 + ni * 16 + r;
#pragma unroll
            for (int tt = 0; tt < 4; ++tt) {
              int lrow = mi * 16 + q * 4 + tt;
              Cs[lrow * 140 + col] = f2bf(acc[mi][ni][tt]);
            }
          }
      }
      __syncthreads();
      {
        int rl = t >> 4, ch = t & 15;
#pragma unroll
        for (int it = 0; it < 4; ++it) {
          int row = it * 16 + rl;
          uint4 v = *(const uint4*)&Cs[row * 140 + ch * 8];
          *(uint4*)(outp + (size_t)(rbase + p * 64 + row) * 1024 + sbase + ch * 8) = v;
        }
      }
    }
  }
}

// ---------------- batched prod GEMM: 256^2 tile, 8 waves, counted vmcnt -----
// R15/R16: m201-style schedule. Grid 256 = 16 channels x 16 tiles (4x4 of
// 256^2), 1 block/CU. LDS 128KB: A0 A1 B0 B1 K-tile buffers (BK=64, dbuf by
// K-tile parity). Per K-tile kt: stage ALL of tile kt+1 into parity^1
// (8 gload_lds/wave, pre-swizzled source srcslot=(lane&7)^(lane>>3));
// vmcnt(8) => tile kt landed (kt+1's 8 stay in flight); barrier; 4 MFMA
// phases (mh x ks, 16 MFMA each, setprio), b-frags reused across mh.
// Reads XOR slot^(row&7): conflict-free b128. XCD locality:
// bp=(b&7)*32+(b>>3) -> each XCD owns 2 channels.
__global__ __launch_bounds__(512, 2) void k_prodgemm(
    const u16* __restrict__ x1tg, const u16* __restrict__ x2tg,
    u16* __restrict__ prod, int cbase) {
  __shared__ u16 ldsbuf[65536];  // 128KB
  int b = blockIdx.x;  // grid 256
  int bp = (b & 7) * 32 + (b >> 3);  // bijective: XCD x -> channels 2x,2x+1
  int cl = bp >> 4, tile = bp & 15;
  int i0 = (tile >> 2) * 256, j0 = (tile & 3) * 256;
  const u16* Ap = x1tg + (size_t)cl * 1048576;
  const u16* Bp = x2tg + (size_t)cl * 1048576;
  u16* Pp = prod + (size_t)(cbase + cl) * 1048576;
  int t = threadIdx.x, lane = t & 63, w = t >> 6;  // 8 waves
  int q = lane >> 4, r = lane & 15, rx = r & 7;
  int wm = w >> 2, wn = w & 3;  // 2 x 4 wave grid; wave output 128 x 64
  int subrow = lane >> 3, srcslot = (lane & 7) ^ (lane >> 3);

#define STAGE(KT)                                                           \
  {                                                                         \
    int pb_ = (KT) & 1;                                                     \
    _Pragma("unroll")                                                       \
    for (int j = 0; j < 8; ++j) {                                           \
      int rg = w * 8 + j;                                                   \
      if (w < 4) {                                                          \
        const u16* src = Ap + (size_t)(i0 + rg * 8 + subrow) * 1024 +       \
                         (KT) * 64 + srcslot * 8;                           \
        __builtin_amdgcn_global_load_lds(                                   \
            (gas1)src, (las3)(ldsbuf + pb_ * 16384 + rg * 512), 16, 0, 0);  \
      } else {                                                              \
        const u16* src = Bp + (size_t)(j0 + (rg - 32) * 8 + subrow) * 1024 +\
                         (KT) * 64 + srcslot * 8;                           \
        __builtin_amdgcn_global_load_lds(                                   \
            (gas1)src, (las3)(ldsbuf + 32768 + pb_ * 16384 + (rg - 32) * 512),\
            16, 0, 0);                                                      \
      }                                                                     \
    }                                                                       \
  }

  f32x4 z4 = {0.f, 0.f, 0.f, 0.f};
  f32x4 acc[8][4];
#pragma unroll
  for (int mi = 0; mi < 8; ++mi)
#pragma unroll
    for (int n = 0; n < 4; ++n) acc[mi][n] = z4;
  bf16x8 bfr[4];

#define PHASE(MH, KS, FRESHB, PB)                                           \
  {                                                                         \
    bf16x8 afr[4];                                                          \
    _Pragma("unroll")                                                       \
    for (int mi = 0; mi < 4; ++mi)                                          \
      afr[mi] = *(const bf16x8*)&ldsbuf[(PB) * 16384 +                      \
          (wm * 128 + (MH) * 64 + mi * 16 + r) * 64 +                       \
          ((((KS) * 4 + q) ^ rx) << 3)];                                    \
    if (FRESHB) {                                                           \
      _Pragma("unroll")                                                     \
      for (int n = 0; n < 4; ++n)                                           \
        bfr[n] = *(const bf16x8*)&ldsbuf[32768 + (PB) * 16384 +             \
            (wn * 64 + n * 16 + r) * 64 + ((((KS) * 4 + q) ^ rx) << 3)];    \
    }                                                                       \
    asm volatile("s_waitcnt lgkmcnt(0)" ::: "memory");                      \
    __builtin_amdgcn_sched_barrier(0);                                      \
    __builtin_amdgcn_s_setprio(1);                                          \
    _Pragma("unroll")                                                       \
    for (int mi = 0; mi < 4; ++mi)                                          \
      _Pragma("unroll")                                                     \
      for (int n = 0; n < 4; ++n)                                           \
        acc[(MH) * 4 + mi][n] =                                             \
            MFMA16(afr[mi], bfr[n], acc[(MH) * 4 + mi][n]);                 \
    __builtin_amdgcn_s_setprio(0);                                          \
  }

  STAGE(0);  // prologue: tile 0 -> parity 0; no wait needed yet
#pragma unroll 1
  for (int kt = 0; kt < 16; ++kt) {
    int pb = kt & 1;
    if (kt < 15) {
      STAGE(kt + 1);  // into parity pb^1: safe vs tile-kt readers
      asm volatile("s_waitcnt vmcnt(8)" ::: "memory");  // tile kt landed
    } else {
      asm volatile("s_waitcnt vmcnt(0)" ::: "memory");
    }
    asm volatile("s_waitcnt lgkmcnt(0)" ::: "memory");
    __builtin_amdgcn_s_barrier();  // all waves see tile kt complete
    asm volatile("" ::: "memory");
    PHASE(0, 0, 1, pb);
    asm volatile("s_waitcnt lgkmcnt(0)" ::: "memory");
    __builtin_amdgcn_s_barrier();
    asm volatile("" ::: "memory");
    PHASE(1, 0, 0, pb);
    asm volatile("s_waitcnt lgkmcnt(0)" ::: "memory");
    __builtin_amdgcn_s_barrier();
    asm volatile("" ::: "memory");
    PHASE(0, 1, 1, pb);
    asm volatile("s_waitcnt lgkmcnt(0)" ::: "memory");
    __builtin_amdgcn_s_barrier();
    asm volatile("" ::: "memory");
    PHASE(1, 1, 0, pb);
    asm volatile("s_waitcnt lgkmcnt(0)" ::: "memory");
    __builtin_amdgcn_s_barrier();  // tile closing: next STAGE may overwrite
    asm volatile("" ::: "memory");
  }
#undef PHASE
#undef STAGE

  // C writeback via LDS, 4 pieces of 64 rows x 256 cols
#pragma unroll 1
  for (int p = 0; p < 4; ++p) {
    if (wm == (p >> 1)) {
      int mh = p & 1;
#pragma unroll
      for (int mi = 0; mi < 4; ++mi)
#pragma unroll
        for (int n = 0; n < 4; ++n)
#pragma unroll
          for (int tt = 0; tt < 4; ++tt) {
            int lr = mi * 16 + q * 4 + tt;
            ldsbuf[lr * 264 + wn * 64 + n * 16 + r] =
                f2bf(acc[mh * 4 + mi][n][tt]);
          }
    }
    asm volatile("s_waitcnt lgkmcnt(0)" ::: "memory");
    __builtin_amdgcn_s_barrier();
    asm volatile("" ::: "memory");
    {
      int row = t >> 3, sg = t & 7;
#pragma unroll
      for (int it = 0; it < 4; ++it) {  // R16 FIX: was it<8 (OOB cols)
        int cu = sg * 8 + it * 64;
        uint4 v = *(const uint4*)&ldsbuf[row * 264 + cu];
        *(uint4*)(Pp + (size_t)(i0 + p * 64 + row) * 1024 + j0 + cu) = v;
      }
    }
    asm volatile("s_waitcnt lgkmcnt(0)" ::: "memory");
    __builtin_amdgcn_s_barrier();
    asm volatile("" ::: "memory");
  }
}

// ---------------- T = [x_i*x_j | eim | prod] @ m3W + b3 (IN PLACE over prod) --
// R12 version: software-pipelined, raw s_barrier + lgkmcnt-only drain;
// PT/xb register-prefetched one chunk ahead; eim row in LDS; store of chunk
// jc-1 overlaps chunk jc staging. 3 barriers per chunk.
__global__ __launch_bounds__(256, 3) void k_buildT(
    const u16* __restrict__ xbg, const unsigned char* __restrict__ eim,
    u16* PT, const float* __restrict__ m3W, const float* __restrict__ m3b,
    float* __restrict__ S, float* __restrict__ SS) {
  __shared__ u16 A[64 * 136];          // 17408 B: [j][k] k=0..63 xi*xj, 64..127 prod^T
  __shared__ u16 Wt[64 * 136];         // 17408 B
  __shared__ u16 scratch[64 * 66];     // 8448 B: PT chunk [p][j] (+pad)
  __shared__ u16 stg[64 * 72];         // 9216 B: output staging [c][j]
  __shared__ unsigned char eimrow[1024];
  __shared__ float xi[64];
  // total 53760 B -> 3 blocks/CU (161280 <= 163840)
  int i = blockIdx.x;  // grid 1024
  int t = threadIdx.x, lane = t & 63, w = t >> 6;
  int q = lane >> 4, r = lane & 15;
  {
    int zidx = i * 256 + t;
    if (zidx < 65536) { S[zidx] = 0.f; SS[zidx] = 0.f; }
  }
  if (t < 64) xi[t] = bf2f(xbg[i * 64 + t]);
  ((u32*)eimrow)[t] = ((const u32*)(eim + (size_t)i * 1024))[t];
  {
    int row = t >> 1, half = t & 1;
    int rsrc = row < 64 ? row : row + 1;  // skip eim row 64
    const float4* gw = (const float4*)(m3W + rsrc * 64 + half * 32);
#pragma unroll
    for (int k = 0; k < 8; ++k) {
      float4 f = gw[k];
      Wt[(half * 32 + 4 * k + 0) * 136 + row] = f2bf(f.x);
      Wt[(half * 32 + 4 * k + 1) * 136 + row] = f2bf(f.y);
      Wt[(half * 32 + 4 * k + 2) * 136 + row] = f2bf(f.z);
      Wt[(half * 32 + 4 * k + 3) * 136 + row] = f2bf(f.w);
    }
  }
  float w64c[4], b3c[4];
#pragma unroll
  for (int ni = 0; ni < 4; ++ni) {
    int cc = ni * 16 + r;
    w64c[ni] = m3W[64 * 64 + cc];
    b3c[ni] = m3b[cc];
  }
  int p4 = t >> 2, q4 = t & 3;  // thread -> (plane/row, 16-elem quarter)
  uint4 pva, pvb, xva, xvb;     // prefetch registers: PT 32B, xb 32B
  {
    const uint4* gp = (const uint4*)(PT + (size_t)p4 * 1048576 + (size_t)i * 1024 + q4 * 16);
    pva = gp[0]; pvb = gp[1];
    const uint4* gx = (const uint4*)(xbg + p4 * 64 + q4 * 16);
    xva = gx[0]; xvb = gx[1];
  }
  for (int jc = 0; jc < 16; ++jc) {
    int j0 = jc * 64;
    // bar1: stg (chunk jc-1) filled & flushed; A/scratch free for reuse
    asm volatile("s_waitcnt lgkmcnt(0)" ::: "memory");
    __builtin_amdgcn_s_barrier();
    asm volatile("" ::: "memory");
    // phase A: stage current chunk from regs into LDS
    {
      u32* sw = (u32*)&scratch[p4 * 66 + q4 * 16];
      sw[0] = pva.x; sw[1] = pva.y; sw[2] = pva.z; sw[3] = pva.w;
      sw[4] = pvb.x; sw[5] = pvb.y; sw[6] = pvb.z; sw[7] = pvb.w;
      u32 xv[8] = {xva.x, xva.y, xva.z, xva.w, xvb.x, xvb.y, xvb.z, xvb.w};
      u32* dst = (u32*)&A[p4 * 136 + q4 * 16];
#pragma unroll
      for (int k = 0; k < 8; ++k) {
        u32 u = xv[k];
        float f0 = bf2f((u16)(u & 0xffffu)) * xi[q4 * 16 + 2 * k];
        float f1 = bf2f((u16)(u >> 16)) * xi[q4 * 16 + 2 * k + 1];
        dst[k] = (u32)f2bf(f0) | ((u32)f2bf(f1) << 16);
      }
    }
    // prefetch chunk jc+1 into regs (consumed next iter; no vmcnt drain at
    // raw barriers, so these stay in flight under phases B/C/D).
    // Hazard-free: reads j in [j0+64,j0+128), stores below write [j0-64,j0).
    if (jc < 15) {
      const uint4* gp = (const uint4*)(PT + (size_t)p4 * 1048576 + (size_t)i * 1024 + (j0 + 64) + q4 * 16);
      pva = gp[0]; pvb = gp[1];
      const uint4* gx = (const uint4*)(xbg + (j0 + 64 + p4) * 64 + q4 * 16);
      xva = gx[0]; xvb = gx[1];
    }
    // overlapped global store of chunk jc-1 from stg
    if (jc > 0) {
      int pl = t >> 3, off = (t & 7) * 8;
#pragma unroll
      for (int k = 0; k < 2; ++k) {
        int plane = k * 32 + pl;
        uint4 v = *(const uint4*)&stg[plane * 72 + off];
        *(uint4*)(PT + (size_t)plane * 1048576 + (size_t)i * 1024 + (j0 - 64) + off) = v;
      }
    }
    // bar2: scratch + A cols 0-63 visible
    asm volatile("s_waitcnt lgkmcnt(0)" ::: "memory");
    __builtin_amdgcn_s_barrier();
    asm volatile("" ::: "memory");
    // phase B: transpose scratch [p][j] -> A cols 64-127 [j][64+p]
#pragma unroll
    for (int jj2 = 0; jj2 < 8; ++jj2) {
      int jr = w * 16 + jj2 * 2;
      u32 two = *(const u32*)&scratch[lane * 66 + jr];
      A[jr * 136 + 64 + lane] = (u16)(two & 0xffffu);
      A[(jr + 1) * 136 + 64 + lane] = (u16)(two >> 16);
    }
    // bar3: A complete
    asm volatile("s_waitcnt lgkmcnt(0)" ::: "memory");
    __builtin_amdgcn_s_barrier();
    asm volatile("" ::: "memory");
    // phase C: MFMA
    f32x4 z4 = {0.f, 0.f, 0.f, 0.f};
    f32x4 acc[4];
#pragma unroll
    for (int ni = 0; ni < 4; ++ni) acc[ni] = z4;
#pragma unroll
    for (int ks = 0; ks < 4; ++ks) {
      bf16x8 af, bfr[4];
      af = *(const bf16x8*)&A[(w * 16 + r) * 136 + ks * 32 + q * 8];
#pragma unroll
      for (int ni = 0; ni < 4; ++ni)
        bfr[ni] = *(const bf16x8*)&Wt[(ni * 16 + r) * 136 + ks * 32 + q * 8];
#pragma unroll
      for (int ni = 0; ni < 4; ++ni) acc[ni] = MFMA16(af, bfr[ni], acc[ni]);
    }
#pragma unroll
    for (int tt = 0; tt < 4; ++tt) {
      int jj = w * 16 + q * 4 + tt;
      float ev = (float)eimrow[j0 + jj];
#pragma unroll
      for (int ni = 0; ni < 4; ++ni)
        acc[ni][tt] = acc[ni][tt] + ev * w64c[ni] + b3c[ni];
    }
    // phase D: acc -> stg [c][j]  (no barrier needed: stg readers of this
    // iteration finished before bar2; next readers wait at bar1 w/ lgkm(0))
#pragma unroll
    for (int ni = 0; ni < 4; ++ni) {
      int cc = ni * 16 + r;
#pragma unroll
      for (int tt = 0; tt < 4; ++tt) {
        int jj = w * 16 + q * 4 + tt;
        stg[cc * 72 + jj] = f2bf(acc[ni][tt]);
      }
    }
  }
  // epilogue: store chunk 15
  asm volatile("s_waitcnt lgkmcnt(0)" ::: "memory");
  __builtin_amdgcn_s_barrier();
  asm volatile("" ::: "memory");
  {
    int pl = t >> 3, off = (t & 7) * 8;
#pragma unroll
    for (int k = 0; k < 2; ++k) {
      int plane = k * 32 + pl;
      uint4 v = *(const uint4*)&stg[plane * 72 + off];
      *(uint4*)(PT + (size_t)plane * 1048576 + (size_t)i * 1024 + 960 + off) = v;
    }
  }
}

// ---------------- graph-norm stats, pass 1: coalesced partial sums ----------
__global__ void k_stats(const u16* __restrict__ Tg, float* __restrict__ S,
                        float* __restrict__ SS) {
  int b = blockIdx.x;  // grid 512 = 64 c x 8 i-chunks
  int c = b >> 3, ic = b & 7;
  int t = threadIdx.x;
  const u16* base = Tg + (size_t)c * 1048576 + (size_t)ic * 131072 + t * 4;
  float s0 = 0.f, s1 = 0.f, s2 = 0.f, s3 = 0.f;
  float q0 = 0.f, q1 = 0.f, q2 = 0.f, q3 = 0.f;
  for (int ii = 0; ii < 128; ++ii) {
    uint2 u = *(const uint2*)(base + (size_t)ii * 1024);
    float v0 = bf2f((u16)(u.x & 0xffffu)), v1 = bf2f((u16)(u.x >> 16));
    float v2 = bf2f((u16)(u.y & 0xffffu)), v3 = bf2f((u16)(u.y >> 16));
    s0 += v0; q0 += v0 * v0;
    s1 += v1; q1 += v1 * v1;
    s2 += v2; q2 += v2 * v2;
    s3 += v3; q3 += v3 * v3;
  }
  int base2 = c * 1024 + t * 4;
  atomicAdd(&S[base2 + 0], s0);
  atomicAdd(&S[base2 + 1], s1);
  atomicAdd(&S[base2 + 2], s2);
  atomicAdd(&S[base2 + 3], s3);
  atomicAdd(&SS[base2 + 0], q0);
  atomicAdd(&SS[base2 + 1], q1);
  atomicAdd(&SS[base2 + 2], q2);
  atomicAdd(&SS[base2 + 3], q3);
}

// ---------------- graph-norm stats, pass 2: finalize ----------
__global__ void k_statsfin(const float* __restrict__ S, const float* __restrict__ SS,
                           const float* __restrict__ gn3w, const float* __restrict__ gn3b,
                           const float* __restrict__ gn3a,
                           float* __restrict__ normA, float* __restrict__ normB) {
  int idx = blockIdx.x * 256 + threadIdx.x;  // grid 256 -> 65536 = j*64+c
  int c = idx & 63, j = idx >> 6;
  float sum = S[c * 1024 + j];
  float ssum = SS[c * 1024 + j];
  float m = sum * (1.f / 1024.f);
  float a = gn3a[c];
  float var = ssum * (1.f / 1024.f) - (2.f * a - a * a) * m * m;
  float sc = gn3w[c] * rsqrtf(fmaxf(var, 0.f) + 1e-5f);
  normA[idx] = sc;
  normB[idx] = gn3b[c] - sc * a * m;
}

// ---------------- gather + symmetric product + final dot ----------------
__global__ void k_final(const u16* __restrict__ Tg, const float* __restrict__ normA,
                        const float* __restrict__ normB, const int* __restrict__ pos,
                        const float* __restrict__ ldW, const float* __restrict__ ldb,
                        float* __restrict__ out) {
  int t = threadIdx.x, w = t >> 6, lane = t & 63;  // grid 2048 x 256, wave/pos
  int p = blockIdx.x * 4 + w;
  int i = pos[2 * p], j = pos[2 * p + 1];
  float t1 = bf2f(Tg[(size_t)lane * 1048576 + (size_t)i * 1024 + j]);
  float y1 = fmaxf(normA[j * 64 + lane] * t1 + normB[j * 64 + lane], 0.f);
  float t2 = bf2f(Tg[(size_t)lane * 1048576 + (size_t)j * 1024 + i]);
  float y2 = fmaxf(normA[i * 64 + lane] * t2 + normB[i * 64 + lane], 0.f);
  float z = y1 * y2 * ldW[lane];
#pragma unroll
  for (int off = 32; off > 0; off >>= 1) z += __shfl_down(z, off, 64);
  if (lane == 0) out[p] = z + ldb[0];
}

extern "C" void kernel_launch(void* const* d_in, const int* in_sizes, int n_in,
                              void* d_out, int out_size, void* d_ws, size_t ws_size,
                              hipStream_t stream) {
  const int* xids   = (const int*)d_in[0];
  const int* ei     = (const int*)d_in[1];
  const int* pos    = (const int*)d_in[2];
  const float* emb  = (const float*)d_in[3];
  const float* gW0  = (const float*)d_in[4];
  const float* gb0  = (const float*)d_in[5];
  const float* gnw0 = (const float*)d_in[6];
  const float* gnb0 = (const float*)d_in[7];
  const float* gna0 = (const float*)d_in[8];
  const float* gW1  = (const float*)d_in[9];
  const float* gb1  = (const float*)d_in[10];
  const float* gnw1 = (const float*)d_in[11];
  const float* gnb1 = (const float*)d_in[12];
  const float* gna1 = (const float*)d_in[13];
  const float* m1W  = (const float*)d_in[14];
  const float* m1b  = (const float*)d_in[15];
  const float* m2W  = (const float*)d_in[16];
  const float* m2b  = (const float*)d_in[17];
  const float* m3W  = (const float*)d_in[18];
  const float* m3b  = (const float*)d_in[19];
  const float* gn3w = (const float*)d_in[20];
  const float* gn3b = (const float*)d_in[21];
  const float* gn3a = (const float*)d_in[22];
  const float* ldW  = (const float*)d_in[23];
  const float* ldb  = (const float*)d_in[24];

  char* ws = (char*)d_ws;
  float* xf   = (float*)(ws + 0);
  float* h    = (float*)(ws + 262144);
  float* agg  = (float*)(ws + 524288);
  float* deg  = (float*)(ws + 786432);
  u16*   xb   = (u16*)(ws + 790528);
  unsigned char* eim = (unsigned char*)(ws + 921600);
  float* normA = (float*)(ws + 1970176);
  float* normB = (float*)(ws + 2232320);
  u16* x1tg = (u16*)(ws + 2494464);
  u16* x2tg = (u16*)(ws + 36048896);
  u16* prod = (u16*)(ws + 69603328);  // later overwritten in place by T
  float* Sp  = (float*)x1tg;          // stats partials overlay dead x1tg
  float* SSp = Sp + 65536;
  float* out = (float*)d_out;

  k_setup<<<1024, 256, 0, stream>>>(xids, emb, xf, deg, (u32*)eim);
  k_edges<<<64, 256, 0, stream>>>(ei, deg, eim);
  // GCN layer 0
  k_gemm_node<<<1024, 64, 0, stream>>>(xf, gW0, gb0, deg, h, agg);
  k_agg<<<4096, 256, 0, stream>>>(ei, deg, h, agg);
  k_gnorm<<<64, 256, 0, stream>>>(agg, gnw0, gnb0, gna0, xf, xb, 0);
  // GCN layer 1
  k_gemm_node<<<1024, 64, 0, stream>>>(xf, gW1, gb1, deg, h, agg);
  k_agg<<<4096, 256, 0, stream>>>(ei, deg, h, agg);
  k_gnorm<<<64, 256, 0, stream>>>(agg, gnw1, gnb1, gna1, xf, xb, 1);
  // pairwise maps + batched 1024^3 GEMM, 4 channel-groups of 16
  for (int g = 0; g < 4; ++g) {
    k_build12<<<512, 256, 0, stream>>>(xb, eim, m1W, m1b, m2W, m2b, x1tg, x2tg, g * 16);
    k_prodgemm<<<256, 512, 0, stream>>>(x1tg, x2tg, prod, g * 16);
  }
  // T tensor (in place over prod) + stats + final
  k_buildT<<<1024, 256, 0, stream>>>(xb, eim, prod, m3W, m3b, Sp, SSp);
  k_stats<<<512, 256, 0, stream>>>(prod, Sp, SSp);
  k_statsfin<<<256, 256, 0, stream>>>(Sp, SSp, gn3w, gn3b, gn3a, normA, normB);
  k_final<<<2048, 256, 0, stream>>>(prod, normA, normB, pos, ldW, ldb, out);
}

// Round 6
// 508.580 us; speedup vs baseline: 1.2677x; 1.2677x over previous
//
#include <hip/hip_runtime.h>

// FWLNet pipeline; see R5-R17 notes.
//
// R17 (from R16 @644.7us): full revert to the best-known R12 configuration.
// R16 counters convicted the 256^2 prodgemm port: 134us cold with 0.17%
// occupancy (grid 256 = 1 block/CU, zero inter-block overlap -> exposed
// straggler tail), ~67us warm vs R11's ~40; it also slowed buildT 66->95
// (dirty-L2 handoff). Reverts:
//  - k_prodgemm: R11 version (128^2, 2-barrier m97 structure, 34KB LDS,
//    4 blocks/CU, grid 1024x256, XCD-aware channel swizzle).
//  - k_buildT: R12 version (66us known-good), with ONE schedule-neutral
//    tweak: phase-D stg writes packed 16x b16 -> 4x b64 (uint2). Addr
//    cc*144+w*32+q*8 is 8B-aligned; bank-pair (4r+2q)%32 = 2-way only
//    (free). Pure LDS-issue diet on the LDS-pipe-bound kernel; no-op if
//    the compiler already merged.
//
// ws layout unchanged (~194.4 MB).

typedef unsigned short u16;
typedef unsigned int u32;

#define DI static __device__ __forceinline__

DI float bf2f(u16 u) { union { u32 i; float f; } v; v.i = ((u32)u) << 16; return v.f; }
DI u16 f2bf(float f) {
  union { float f; u32 i; } v; v.f = f;
  u32 u = v.i;
  return (u16)((u + 0x7fffu + ((u >> 16) & 1u)) >> 16);
}

typedef __bf16 bf16x8 __attribute__((ext_vector_type(8)));
typedef float f32x4 __attribute__((ext_vector_type(4)));

#define MFMA16(a, b, c) __builtin_amdgcn_mfma_f32_16x16x32_bf16((a), (b), (c), 0, 0, 0)

typedef const __attribute__((address_space(1))) u32* gas1;
typedef __attribute__((address_space(3))) u32* las3;

// ---------------- node pipeline ----------------

__global__ void k_setup(const int* __restrict__ xids, const float* __restrict__ emb,
                        float* __restrict__ xf, float* __restrict__ deg,
                        u32* __restrict__ eimu) {
  int g = blockIdx.x * 256 + threadIdx.x;  // grid 1024
  if (g < 262144) eimu[g] = 0u;
  if (g < 1024) deg[g] = 1.0f;  // self-loop
  if (g < 65536) {
    int i = g >> 6, d = g & 63;
    xf[g] = emb[xids[i] * 64 + d];
  }
}

__global__ void k_edges(const int* __restrict__ ei, float* __restrict__ deg,
                        unsigned char* __restrict__ eim) {
  int e = blockIdx.x * 256 + threadIdx.x;  // grid 64
  if (e < 16384) {
    int s = ei[e], d = ei[16384 + e];
    atomicAdd(&deg[d], 1.0f);
    eim[s * 1024 + d] = 1;
  }
}

__global__ void k_gemm_node(const float* __restrict__ xf, const float* __restrict__ W,
                            const float* __restrict__ gb, const float* __restrict__ deg,
                            float* __restrict__ h, float* __restrict__ agg) {
  __shared__ float xrow[64];
  int i = blockIdx.x, c = threadIdx.x;  // grid 1024 x 64
  xrow[c] = xf[i * 64 + c];
  __syncthreads();
  float s = 0.f;
#pragma unroll
  for (int d = 0; d < 64; ++d) s += xrow[d] * W[d * 64 + c];
  h[i * 64 + c] = s;
  agg[i * 64 + c] = s / deg[i] + gb[c];
}

__global__ void k_agg(const int* __restrict__ ei, const float* __restrict__ deg,
                      const float* __restrict__ h, float* __restrict__ agg) {
  int g = blockIdx.x * 256 + threadIdx.x;  // grid 4096 -> e x c
  int e = g >> 6, c = g & 63;
  int s = ei[e], d = ei[16384 + e];
  float nrm = rsqrtf(deg[s]) * rsqrtf(deg[d]);
  atomicAdd(&agg[d * 64 + c], nrm * h[s * 64 + c]);
}

__global__ void k_gnorm(const float* __restrict__ agg, const float* __restrict__ gw,
                        const float* __restrict__ gbb, const float* __restrict__ ga,
                        float* __restrict__ xf, u16* __restrict__ xb, int last) {
  int c = blockIdx.x, t = threadIdx.x;  // grid 64 x 256
  float s = 0.f, ss = 0.f;
  for (int i = t; i < 1024; i += 256) {
    float v = agg[i * 64 + c];
    s += v; ss += v * v;
  }
  __shared__ float Ls[256], Lss[256];
  Ls[t] = s; Lss[t] = ss;
  __syncthreads();
  for (int off = 128; off > 0; off >>= 1) {
    if (t < off) { Ls[t] += Ls[t + off]; Lss[t] += Lss[t + off]; }
    __syncthreads();
  }
  float m = Ls[0] * (1.f / 1024.f);
  float a = ga[c];
  float var = Lss[0] * (1.f / 1024.f) - (2.f * a - a * a) * m * m;
  float sc = gw[c] * rsqrtf(fmaxf(var, 0.f) + 1e-5f);
  float bb = gbb[c];
  for (int i = t; i < 1024; i += 256) {
    float v = agg[i * 64 + c];
    float y = fmaxf(sc * (v - a * m) + bb, 0.f);
    xf[i * 64 + c] = y;
    if (last) xb[i * 64 + c] = f2bf(y);
  }
}

// ---------------- x1t / x2T builder: 4 channels per block ----------------
__global__ __launch_bounds__(256, 2) void k_build12(
    const u16* __restrict__ xbg, const unsigned char* __restrict__ eim,
    const float* __restrict__ m1W, const float* __restrict__ m1b,
    const float* __restrict__ m2W, const float* __restrict__ m2b,
    u16* __restrict__ x1tg, u16* __restrict__ x2tg, int cbase) {
  __shared__ u16 As[128 * 80];
  __shared__ u16 Bs[128 * 80];
  __shared__ u16 Cs[64 * 140];
  __shared__ unsigned char El[128 * 132];
  __shared__ float wsc[64];
  int b = blockIdx.x;  // grid 512 = 2(which) x 64 tiles x 4 channel-quads
  int cg = b & 3;
  int rest = b >> 2;
  int which = rest >> 6;
  int t6 = rest & 63;
  int rbase = (t6 >> 3) * 128, sbase = (t6 & 7) * 128;
  const float* W = which ? m2W : m1W;
  const float* bias = which ? m2b : m1b;
  u16* outg = which ? x2tg : x1tg;
  int t = threadIdx.x;
  {
    int row = t >> 1, half = t & 1;
    const u32* gB = (const u32*)(xbg + (sbase + row) * 64 + half * 32);
    u32* dstB = (u32*)&Bs[row * 80 + half * 32];
#pragma unroll
    for (int k = 0; k < 16; ++k) dstB[k] = gB[k];
    int ab = which ? sbase : rbase;
    int bb = which ? rbase : sbase;
    const u32* gE = (const u32*)(eim + (size_t)(ab + row) * 1024 + bb + half * 64);
    u32* dstE = (u32*)&El[row * 132 + half * 64];
#pragma unroll
    for (int k = 0; k < 16; ++k) dstE[k] = gE[k];
  }
  int lane = t & 63, w = t >> 6;
  int q = lane >> 4, r = lane & 15;
  int wr = w >> 1, wc = w & 1;
  for (int ci = 0; ci < 4; ++ci) {
    int cl = cg * 4 + ci;
    int c = cbase + cl;
    if (t < 64) wsc[t] = W[t * 64 + c];
    __syncthreads();
    {
      int row = t >> 1, half = t & 1;
      const u32* ga = (const u32*)(xbg + (rbase + row) * 64 + half * 32);
      u32* dstA = (u32*)&As[row * 80 + half * 32];
#pragma unroll
      for (int k = 0; k < 16; ++k) {
        u32 u = ga[k];
        float f0 = bf2f((u16)(u & 0xffffu)) * wsc[half * 32 + 2 * k];
        float f1 = bf2f((u16)(u >> 16)) * wsc[half * 32 + 2 * k + 1];
        dstA[k] = (u32)f2bf(f0) | ((u32)f2bf(f1) << 16);
      }
    }
    __syncthreads();
    f32x4 z4 = {0.f, 0.f, 0.f, 0.f};
    f32x4 acc[4][4];
#pragma unroll
    for (int mi = 0; mi < 4; ++mi)
#pragma unroll
      for (int ni = 0; ni < 4; ++ni) acc[mi][ni] = z4;
#pragma unroll
    for (int ks = 0; ks < 2; ++ks) {
      bf16x8 af[4], bfr[4];
#pragma unroll
      for (int mi = 0; mi < 4; ++mi)
        af[mi] = *(const bf16x8*)&As[(wr * 64 + mi * 16 + r) * 80 + ks * 32 + q * 8];
#pragma unroll
      for (int ni = 0; ni < 4; ++ni)
        bfr[ni] = *(const bf16x8*)&Bs[(wc * 64 + ni * 16 + r) * 80 + ks * 32 + q * 8];
#pragma unroll
      for (int mi = 0; mi < 4; ++mi)
#pragma unroll
        for (int ni = 0; ni < 4; ++ni) acc[mi][ni] = MFMA16(af[mi], bfr[ni], acc[mi][ni]);
    }
    float w64 = W[64 * 64 + c];
    float bsv = bias[c];
#pragma unroll
    for (int mi = 0; mi < 4; ++mi) {
#pragma unroll
      for (int ni = 0; ni < 4; ++ni) {
        int col = wc * 64 + ni * 16 + r;
#pragma unroll
        for (int tt = 0; tt < 4; ++tt) {
          int row2 = wr * 64 + mi * 16 + q * 4 + tt;
          float e = (float)(which ? El[col * 132 + row2] : El[row2 * 132 + col]);
          acc[mi][ni][tt] = fmaxf(acc[mi][ni][tt] + e * w64 + bsv, 0.f);
        }
      }
    }
    u16* outp = outg + (size_t)cl * 1048576;
#pragma unroll
    for (int p = 0; p < 2; ++p) {
      __syncthreads();
      if (wr == p) {
#pragma unroll
        for (int mi = 0; mi < 4; ++mi)
#pragma unroll
          for (int ni = 0; ni < 4; ++ni) {
            int col = wc * 64 + ni * 16 + r;
#pragma unroll
            for (int tt = 0; tt < 4; ++tt) {
              int lrow = mi * 16 + q * 4 + tt;
              Cs[lrow * 140 + col] = f2bf(acc[mi][ni][tt]);
            }
          }
      }
      __syncthreads();
      {
        int rl = t >> 4, ch = t & 15;
#pragma unroll
        for (int it = 0; it < 4; ++it) {
          int row = it * 16 + rl;
          uint4 v = *(const uint4*)&Cs[row * 140 + ch * 8];
          *(uint4*)(outp + (size_t)(rbase + p * 64 + row) * 1024 + sbase + ch * 8) = v;
        }
      }
    }
  }
}

// ---------------- batched prod GEMM (16 channels per launch) ----------------
// R11 version (restored): XCD-aware block swizzle — all 64 tiles of one
// channel land on one XCD consecutively: per-XCD A+B = 4MB = L2 capacity.
__global__ __launch_bounds__(256, 4) void k_prodgemm(
    const u16* __restrict__ x1tg, const u16* __restrict__ x2tg,
    u16* __restrict__ prod, int cbase) {
  __shared__ u16 pool[17408];
  int b = blockIdx.x;  // grid 1024
  int cl = (b & 7) + ((b >> 9) << 3);   // channel: XCD x gets cl=x then cl=x+8
  int tile = (b >> 3) & 63;             // 64 tiles of that channel, in order
  int i0 = (tile >> 3) * 128, j0 = (tile & 7) * 128;
  const u16* Ap = x1tg + (size_t)cl * 1048576;
  const u16* Bp = x2tg + (size_t)cl * 1048576;
  u16* Pp = prod + (size_t)(cbase + cl) * 1048576;
  int t = threadIdx.x, lane = t & 63, w = t >> 6;
  int q = lane >> 4, r = lane & 15;
  int wr = w >> 1, wc = w & 1;
  int lrow = lane >> 3, lcol = (lane & 7) * 8;
  f32x4 z4 = {0.f, 0.f, 0.f, 0.f};
  f32x4 acc[4][4];
#pragma unroll
  for (int mi = 0; mi < 4; ++mi)
#pragma unroll
    for (int ni = 0; ni < 4; ++ni) acc[mi][ni] = z4;
  for (int kk = 0; kk < 1024; kk += 64) {
    __syncthreads();
#pragma unroll
    for (int s8 = 0; s8 < 4; ++s8) {
      int rowbase = w * 32 + s8 * 8;
      int grow = rowbase + lrow;
      __builtin_amdgcn_global_load_lds(
          (gas1)(Ap + (size_t)(i0 + grow) * 1024 + kk + lcol),
          (las3)&pool[rowbase * 64], 16, 0, 0);
      __builtin_amdgcn_global_load_lds(
          (gas1)(Bp + (size_t)(j0 + grow) * 1024 + kk + lcol),
          (las3)&pool[8192 + rowbase * 64], 16, 0, 0);
    }
    __syncthreads();
#pragma unroll
    for (int ks = 0; ks < 2; ++ks) {
      bf16x8 af[4], bfr[4];
#pragma unroll
      for (int mi = 0; mi < 4; ++mi)
        af[mi] = *(const bf16x8*)&pool[(wr * 64 + mi * 16 + r) * 64 + ks * 32 + q * 8];
#pragma unroll
      for (int ni = 0; ni < 4; ++ni)
        bfr[ni] = *(const bf16x8*)&pool[8192 + (wc * 64 + ni * 16 + r) * 64 + ks * 32 + q * 8];
#pragma unroll
      for (int mi = 0; mi < 4; ++mi)
#pragma unroll
        for (int ni = 0; ni < 4; ++ni) acc[mi][ni] = MFMA16(af[mi], bfr[ni], acc[mi][ni]);
    }
  }
  __syncthreads();
#pragma unroll
  for (int mi = 0; mi < 4; ++mi)
#pragma unroll
    for (int ni = 0; ni < 4; ++ni) {
      int col = wc * 64 + ni * 16 + r;
#pragma unroll
      for (int tt = 0; tt < 4; ++tt) {
        int row2 = wr * 64 + mi * 16 + q * 4 + tt;
        pool[row2 * 136 + col] = f2bf(acc[mi][ni][tt]);
      }
    }
  __syncthreads();
  {
    int rseg = t >> 4, cseg = t & 15;
#pragma unroll
    for (int it = 0; it < 8; ++it) {
      int row = it * 16 + rseg;
      uint4 v = *(const uint4*)&pool[row * 136 + cseg * 8];
      *(uint4*)(Pp + (size_t)(i0 + row) * 1024 + j0 + cseg * 8) = v;
    }
  }
}

// ---------------- T = [x_i*x_j | eim | prod] @ m3W + b3 (IN PLACE over prod) --
// R12 version: software-pipelined, raw s_barrier + lgkmcnt-only drain;
// PT/xb register-prefetched one chunk ahead; eim row in LDS; store of chunk
// jc-1 overlaps chunk jc staging. 3 barriers per chunk.
// R17: phase-D stg writes packed 16x b16 -> 4x b64 (only change).
__global__ __launch_bounds__(256, 3) void k_buildT(
    const u16* __restrict__ xbg, const unsigned char* __restrict__ eim,
    u16* PT, const float* __restrict__ m3W, const float* __restrict__ m3b,
    float* __restrict__ S, float* __restrict__ SS) {
  __shared__ u16 A[64 * 136];          // 17408 B: [j][k] k=0..63 xi*xj, 64..127 prod^T
  __shared__ u16 Wt[64 * 136];         // 17408 B
  __shared__ u16 scratch[64 * 66];     // 8448 B: PT chunk [p][j] (+pad)
  __shared__ __align__(16) u16 stg[64 * 72];  // 9216 B: output staging [c][j]
  __shared__ unsigned char eimrow[1024];
  __shared__ float xi[64];
  // total 53760 B -> 3 blocks/CU (161280 <= 163840)
  int i = blockIdx.x;  // grid 1024
  int t = threadIdx.x, lane = t & 63, w = t >> 6;
  int q = lane >> 4, r = lane & 15;
  {
    int zidx = i * 256 + t;
    if (zidx < 65536) { S[zidx] = 0.f; SS[zidx] = 0.f; }
  }
  if (t < 64) xi[t] = bf2f(xbg[i * 64 + t]);
  ((u32*)eimrow)[t] = ((const u32*)(eim + (size_t)i * 1024))[t];
  {
    int row = t >> 1, half = t & 1;
    int rsrc = row < 64 ? row : row + 1;  // skip eim row 64
    const float4* gw = (const float4*)(m3W + rsrc * 64 + half * 32);
#pragma unroll
    for (int k = 0; k < 8; ++k) {
      float4 f = gw[k];
      Wt[(half * 32 + 4 * k + 0) * 136 + row] = f2bf(f.x);
      Wt[(half * 32 + 4 * k + 1) * 136 + row] = f2bf(f.y);
      Wt[(half * 32 + 4 * k + 2) * 136 + row] = f2bf(f.z);
      Wt[(half * 32 + 4 * k + 3) * 136 + row] = f2bf(f.w);
    }
  }
  float w64c[4], b3c[4];
#pragma unroll
  for (int ni = 0; ni < 4; ++ni) {
    int cc = ni * 16 + r;
    w64c[ni] = m3W[64 * 64 + cc];
    b3c[ni] = m3b[cc];
  }
  int p4 = t >> 2, q4 = t & 3;  // thread -> (plane/row, 16-elem quarter)
  uint4 pva, pvb, xva, xvb;     // prefetch registers: PT 32B, xb 32B
  {
    const uint4* gp = (const uint4*)(PT + (size_t)p4 * 1048576 + (size_t)i * 1024 + q4 * 16);
    pva = gp[0]; pvb = gp[1];
    const uint4* gx = (const uint4*)(xbg + p4 * 64 + q4 * 16);
    xva = gx[0]; xvb = gx[1];
  }
  for (int jc = 0; jc < 16; ++jc) {
    int j0 = jc * 64;
    // bar1: stg (chunk jc-1) filled & flushed; A/scratch free for reuse
    asm volatile("s_waitcnt lgkmcnt(0)" ::: "memory");
    __builtin_amdgcn_s_barrier();
    asm volatile("" ::: "memory");
    // phase A: stage current chunk from regs into LDS
    {
      u32* sw = (u32*)&scratch[p4 * 66 + q4 * 16];
      sw[0] = pva.x; sw[1] = pva.y; sw[2] = pva.z; sw[3] = pva.w;
      sw[4] = pvb.x; sw[5] = pvb.y; sw[6] = pvb.z; sw[7] = pvb.w;
      u32 xv[8] = {xva.x, xva.y, xva.z, xva.w, xvb.x, xvb.y, xvb.z, xvb.w};
      u32* dst = (u32*)&A[p4 * 136 + q4 * 16];
#pragma unroll
      for (int k = 0; k < 8; ++k) {
        u32 u = xv[k];
        float f0 = bf2f((u16)(u & 0xffffu)) * xi[q4 * 16 + 2 * k];
        float f1 = bf2f((u16)(u >> 16)) * xi[q4 * 16 + 2 * k + 1];
        dst[k] = (u32)f2bf(f0) | ((u32)f2bf(f1) << 16);
      }
    }
    // prefetch chunk jc+1 into regs (consumed next iter; no vmcnt drain at
    // raw barriers, so these stay in flight under phases B/C/D).
    // Hazard-free: reads j in [j0+64,j0+128), stores below write [j0-64,j0).
    if (jc < 15) {
      const uint4* gp = (const uint4*)(PT + (size_t)p4 * 1048576 + (size_t)i * 1024 + (j0 + 64) + q4 * 16);
      pva = gp[0]; pvb = gp[1];
      const uint4* gx = (const uint4*)(xbg + (j0 + 64 + p4) * 64 + q4 * 16);
      xva = gx[0]; xvb = gx[1];
    }
    // overlapped global store of chunk jc-1 from stg
    if (jc > 0) {
      int pl = t >> 3, off = (t & 7) * 8;
#pragma unroll
      for (int k = 0; k < 2; ++k) {
        int plane = k * 32 + pl;
        uint4 v = *(const uint4*)&stg[plane * 72 + off];
        *(uint4*)(PT + (size_t)plane * 1048576 + (size_t)i * 1024 + (j0 - 64) + off) = v;
      }
    }
    // bar2: scratch + A cols 0-63 visible
    asm volatile("s_waitcnt lgkmcnt(0)" ::: "memory");
    __builtin_amdgcn_s_barrier();
    asm volatile("" ::: "memory");
    // phase B: transpose scratch [p][j] -> A cols 64-127 [j][64+p]
#pragma unroll
    for (int jj2 = 0; jj2 < 8; ++jj2) {
      int jr = w * 16 + jj2 * 2;
      u32 two = *(const u32*)&scratch[lane * 66 + jr];
      A[jr * 136 + 64 + lane] = (u16)(two & 0xffffu);
      A[(jr + 1) * 136 + 64 + lane] = (u16)(two >> 16);
    }
    // bar3: A complete
    asm volatile("s_waitcnt lgkmcnt(0)" ::: "memory");
    __builtin_amdgcn_s_barrier();
    asm volatile("" ::: "memory");
    // phase C: MFMA
    f32x4 z4 = {0.f, 0.f, 0.f, 0.f};
    f32x4 acc[4];
#pragma unroll
    for (int ni = 0; ni < 4; ++ni) acc[ni] = z4;
#pragma unroll
    for (int ks = 0; ks < 4; ++ks) {
      bf16x8 af, bfr[4];
      af = *(const bf16x8*)&A[(w * 16 + r) * 136 + ks * 32 + q * 8];
#pragma unroll
      for (int ni = 0; ni < 4; ++ni)
        bfr[ni] = *(const bf16x8*)&Wt[(ni * 16 + r) * 136 + ks * 32 + q * 8];
#pragma unroll
      for (int ni = 0; ni < 4; ++ni) acc[ni] = MFMA16(af, bfr[ni], acc[ni]);
    }
#pragma unroll
    for (int tt = 0; tt < 4; ++tt) {
      int jj = w * 16 + q * 4 + tt;
      float ev = (float)eimrow[j0 + jj];
#pragma unroll
      for (int ni = 0; ni < 4; ++ni)
        acc[ni][tt] = acc[ni][tt] + ev * w64c[ni] + b3c[ni];
    }
    // phase D: acc -> stg [c][j], packed b64 (R17: was 16 scalar b16)
#pragma unroll
    for (int ni = 0; ni < 4; ++ni) {
      int cc = ni * 16 + r;
      u32 lo = (u32)f2bf(acc[ni][0]) | ((u32)f2bf(acc[ni][1]) << 16);
      u32 hi = (u32)f2bf(acc[ni][2]) | ((u32)f2bf(acc[ni][3]) << 16);
      uint2 vv; vv.x = lo; vv.y = hi;
      *(uint2*)&stg[cc * 72 + w * 16 + q * 4] = vv;
    }
  }
  // epilogue: store chunk 15
  asm volatile("s_waitcnt lgkmcnt(0)" ::: "memory");
  __builtin_amdgcn_s_barrier();
  asm volatile("" ::: "memory");
  {
    int pl = t >> 3, off = (t & 7) * 8;
#pragma unroll
    for (int k = 0; k < 2; ++k) {
      int plane = k * 32 + pl;
      uint4 v = *(const uint4*)&stg[plane * 72 + off];
      *(uint4*)(PT + (size_t)plane * 1048576 + (size_t)i * 1024 + 960 + off) = v;
    }
  }
}

// ---------------- graph-norm stats, pass 1: coalesced partial sums ----------
__global__ void k_stats(const u16* __restrict__ Tg, float* __restrict__ S,
                        float* __restrict__ SS) {
  int b = blockIdx.x;  // grid 512 = 64 c x 8 i-chunks
  int c = b >> 3, ic = b & 7;
  int t = threadIdx.x;
  const u16* base = Tg + (size_t)c * 1048576 + (size_t)ic * 131072 + t * 4;
  float s0 = 0.f, s1 = 0.f, s2 = 0.f, s3 = 0.f;
  float q0 = 0.f, q1 = 0.f, q2 = 0.f, q3 = 0.f;
  for (int ii = 0; ii < 128; ++ii) {
    uint2 u = *(const uint2*)(base + (size_t)ii * 1024);
    float v0 = bf2f((u16)(u.x & 0xffffu)), v1 = bf2f((u16)(u.x >> 16));
    float v2 = bf2f((u16)(u.y & 0xffffu)), v3 = bf2f((u16)(u.y >> 16));
    s0 += v0; q0 += v0 * v0;
    s1 += v1; q1 += v1 * v1;
    s2 += v2; q2 += v2 * v2;
    s3 += v3; q3 += v3 * v3;
  }
  int base2 = c * 1024 + t * 4;
  atomicAdd(&S[base2 + 0], s0);
  atomicAdd(&S[base2 + 1], s1);
  atomicAdd(&S[base2 + 2], s2);
  atomicAdd(&S[base2 + 3], s3);
  atomicAdd(&SS[base2 + 0], q0);
  atomicAdd(&SS[base2 + 1], q1);
  atomicAdd(&SS[base2 + 2], q2);
  atomicAdd(&SS[base2 + 3], q3);
}

// ---------------- graph-norm stats, pass 2: finalize ----------
__global__ void k_statsfin(const float* __restrict__ S, const float* __restrict__ SS,
                           const float* __restrict__ gn3w, const float* __restrict__ gn3b,
                           const float* __restrict__ gn3a,
                           float* __restrict__ normA, float* __restrict__ normB) {
  int idx = blockIdx.x * 256 + threadIdx.x;  // grid 256 -> 65536 = j*64+c
  int c = idx & 63, j = idx >> 6;
  float sum = S[c * 1024 + j];
  float ssum = SS[c * 1024 + j];
  float m = sum * (1.f / 1024.f);
  float a = gn3a[c];
  float var = ssum * (1.f / 1024.f) - (2.f * a - a * a) * m * m;
  float sc = gn3w[c] * rsqrtf(fmaxf(var, 0.f) + 1e-5f);
  normA[idx] = sc;
  normB[idx] = gn3b[c] - sc * a * m;
}

// ---------------- gather + symmetric product + final dot ----------------
__global__ void k_final(const u16* __restrict__ Tg, const float* __restrict__ normA,
                        const float* __restrict__ normB, const int* __restrict__ pos,
                        const float* __restrict__ ldW, const float* __restrict__ ldb,
                        float* __restrict__ out) {
  int t = threadIdx.x, w = t >> 6, lane = t & 63;  // grid 2048 x 256, wave/pos
  int p = blockIdx.x * 4 + w;
  int i = pos[2 * p], j = pos[2 * p + 1];
  float t1 = bf2f(Tg[(size_t)lane * 1048576 + (size_t)i * 1024 + j]);
  float y1 = fmaxf(normA[j * 64 + lane] * t1 + normB[j * 64 + lane], 0.f);
  float t2 = bf2f(Tg[(size_t)lane * 1048576 + (size_t)j * 1024 + i]);
  float y2 = fmaxf(normA[i * 64 + lane] * t2 + normB[i * 64 + lane], 0.f);
  float z = y1 * y2 * ldW[lane];
#pragma unroll
  for (int off = 32; off > 0; off >>= 1) z += __shfl_down(z, off, 64);
  if (lane == 0) out[p] = z + ldb[0];
}

extern "C" void kernel_launch(void* const* d_in, const int* in_sizes, int n_in,
                              void* d_out, int out_size, void* d_ws, size_t ws_size,
                              hipStream_t stream) {
  const int* xids   = (const int*)d_in[0];
  const int* ei     = (const int*)d_in[1];
  const int* pos    = (const int*)d_in[2];
  const float* emb  = (const float*)d_in[3];
  const float* gW0  = (const float*)d_in[4];
  const float* gb0  = (const float*)d_in[5];
  const float* gnw0 = (const float*)d_in[6];
  const float* gnb0 = (const float*)d_in[7];
  const float* gna0 = (const float*)d_in[8];
  const float* gW1  = (const float*)d_in[9];
  const float* gb1  = (const float*)d_in[10];
  const float* gnw1 = (const float*)d_in[11];
  const float* gnb1 = (const float*)d_in[12];
  const float* gna1 = (const float*)d_in[13];
  const float* m1W  = (const float*)d_in[14];
  const float* m1b  = (const float*)d_in[15];
  const float* m2W  = (const float*)d_in[16];
  const float* m2b  = (const float*)d_in[17];
  const float* m3W  = (const float*)d_in[18];
  const float* m3b  = (const float*)d_in[19];
  const float* gn3w = (const float*)d_in[20];
  const float* gn3b = (const float*)d_in[21];
  const float* gn3a = (const float*)d_in[22];
  const float* ldW  = (const float*)d_in[23];
  const float* ldb  = (const float*)d_in[24];

  char* ws = (char*)d_ws;
  float* xf   = (float*)(ws + 0);
  float* h    = (float*)(ws + 262144);
  float* agg  = (float*)(ws + 524288);
  float* deg  = (float*)(ws + 786432);
  u16*   xb   = (u16*)(ws + 790528);
  unsigned char* eim = (unsigned char*)(ws + 921600);
  float* normA = (float*)(ws + 1970176);
  float* normB = (float*)(ws + 2232320);
  u16* x1tg = (u16*)(ws + 2494464);
  u16* x2tg = (u16*)(ws + 36048896);
  u16* prod = (u16*)(ws + 69603328);  // later overwritten in place by T
  float* Sp  = (float*)x1tg;          // stats partials overlay dead x1tg
  float* SSp = Sp + 65536;
  float* out = (float*)d_out;

  k_setup<<<1024, 256, 0, stream>>>(xids, emb, xf, deg, (u32*)eim);
  k_edges<<<64, 256, 0, stream>>>(ei, deg, eim);
  // GCN layer 0
  k_gemm_node<<<1024, 64, 0, stream>>>(xf, gW0, gb0, deg, h, agg);
  k_agg<<<4096, 256, 0, stream>>>(ei, deg, h, agg);
  k_gnorm<<<64, 256, 0, stream>>>(agg, gnw0, gnb0, gna0, xf, xb, 0);
  // GCN layer 1
  k_gemm_node<<<1024, 64, 0, stream>>>(xf, gW1, gb1, deg, h, agg);
  k_agg<<<4096, 256, 0, stream>>>(ei, deg, h, agg);
  k_gnorm<<<64, 256, 0, stream>>>(agg, gnw1, gnb1, gna1, xf, xb, 1);
  // pairwise maps + batched 1024^3 GEMM, 4 channel-groups of 16
  for (int g = 0; g < 4; ++g) {
    k_build12<<<512, 256, 0, stream>>>(xb, eim, m1W, m1b, m2W, m2b, x1tg, x2tg, g * 16);
    k_prodgemm<<<1024, 256, 0, stream>>>(x1tg, x2tg, prod, g * 16);
  }
  // T tensor (in place over prod) + stats + final
  k_buildT<<<1024, 256, 0, stream>>>(xb, eim, prod, m3W, m3b, Sp, SSp);
  k_stats<<<512, 256, 0, stream>>>(prod, Sp, SSp);
  k_statsfin<<<256, 256, 0, stream>>>(Sp, SSp, gn3w, gn3b, gn3a, normA, normB);
  k_final<<<2048, 256, 0, stream>>>(prod, normA, normB, pos, ldW, ldb, out);
}

// Round 7
// 505.407 us; speedup vs baseline: 1.2757x; 1.0063x over previous
//
#include <hip/hip_runtime.h>

// FWLNet pipeline; see R5-R18 notes.
//
// R18 (from R17 @508.6us): buildT is TAIL-BOUND. Occupancy 23% vs 37.5%
// expected at 3 blocks/CU => ~58% of dispatch time runs with 1 block/CU
// (grid 1024 over 768 resident slots leaves a 256-block tail whose
// latency-dominated critical path doesn't shrink when alone). Fix: split
// each row's j-range across 2 blocks -> grid 2048, 8 chunks/block. Inner
// code identical. Hazards: (i,0) writes cols [0,512), (i,1) reads PT cols
// [512,1024) -- disjoint; jc8<7 prefetch guard keeps all PT reads inside
// the block's own column half; duplicate S/SS zeroing idempotent.
// Everything else unchanged from R17 (= R12 best-known config).
//
// ws layout unchanged (~194.4 MB).

typedef unsigned short u16;
typedef unsigned int u32;

#define DI static __device__ __forceinline__

DI float bf2f(u16 u) { union { u32 i; float f; } v; v.i = ((u32)u) << 16; return v.f; }
DI u16 f2bf(float f) {
  union { float f; u32 i; } v; v.f = f;
  u32 u = v.i;
  return (u16)((u + 0x7fffu + ((u >> 16) & 1u)) >> 16);
}

typedef __bf16 bf16x8 __attribute__((ext_vector_type(8)));
typedef float f32x4 __attribute__((ext_vector_type(4)));

#define MFMA16(a, b, c) __builtin_amdgcn_mfma_f32_16x16x32_bf16((a), (b), (c), 0, 0, 0)

typedef const __attribute__((address_space(1))) u32* gas1;
typedef __attribute__((address_space(3))) u32* las3;

// ---------------- node pipeline ----------------

__global__ void k_setup(const int* __restrict__ xids, const float* __restrict__ emb,
                        float* __restrict__ xf, float* __restrict__ deg,
                        u32* __restrict__ eimu) {
  int g = blockIdx.x * 256 + threadIdx.x;  // grid 1024
  if (g < 262144) eimu[g] = 0u;
  if (g < 1024) deg[g] = 1.0f;  // self-loop
  if (g < 65536) {
    int i = g >> 6, d = g & 63;
    xf[g] = emb[xids[i] * 64 + d];
  }
}

__global__ void k_edges(const int* __restrict__ ei, float* __restrict__ deg,
                        unsigned char* __restrict__ eim) {
  int e = blockIdx.x * 256 + threadIdx.x;  // grid 64
  if (e < 16384) {
    int s = ei[e], d = ei[16384 + e];
    atomicAdd(&deg[d], 1.0f);
    eim[s * 1024 + d] = 1;
  }
}

__global__ void k_gemm_node(const float* __restrict__ xf, const float* __restrict__ W,
                            const float* __restrict__ gb, const float* __restrict__ deg,
                            float* __restrict__ h, float* __restrict__ agg) {
  __shared__ float xrow[64];
  int i = blockIdx.x, c = threadIdx.x;  // grid 1024 x 64
  xrow[c] = xf[i * 64 + c];
  __syncthreads();
  float s = 0.f;
#pragma unroll
  for (int d = 0; d < 64; ++d) s += xrow[d] * W[d * 64 + c];
  h[i * 64 + c] = s;
  agg[i * 64 + c] = s / deg[i] + gb[c];
}

__global__ void k_agg(const int* __restrict__ ei, const float* __restrict__ deg,
                      const float* __restrict__ h, float* __restrict__ agg) {
  int g = blockIdx.x * 256 + threadIdx.x;  // grid 4096 -> e x c
  int e = g >> 6, c = g & 63;
  int s = ei[e], d = ei[16384 + e];
  float nrm = rsqrtf(deg[s]) * rsqrtf(deg[d]);
  atomicAdd(&agg[d * 64 + c], nrm * h[s * 64 + c]);
}

__global__ void k_gnorm(const float* __restrict__ agg, const float* __restrict__ gw,
                        const float* __restrict__ gbb, const float* __restrict__ ga,
                        float* __restrict__ xf, u16* __restrict__ xb, int last) {
  int c = blockIdx.x, t = threadIdx.x;  // grid 64 x 256
  float s = 0.f, ss = 0.f;
  for (int i = t; i < 1024; i += 256) {
    float v = agg[i * 64 + c];
    s += v; ss += v * v;
  }
  __shared__ float Ls[256], Lss[256];
  Ls[t] = s; Lss[t] = ss;
  __syncthreads();
  for (int off = 128; off > 0; off >>= 1) {
    if (t < off) { Ls[t] += Ls[t + off]; Lss[t] += Lss[t + off]; }
    __syncthreads();
  }
  float m = Ls[0] * (1.f / 1024.f);
  float a = ga[c];
  float var = Lss[0] * (1.f / 1024.f) - (2.f * a - a * a) * m * m;
  float sc = gw[c] * rsqrtf(fmaxf(var, 0.f) + 1e-5f);
  float bb = gbb[c];
  for (int i = t; i < 1024; i += 256) {
    float v = agg[i * 64 + c];
    float y = fmaxf(sc * (v - a * m) + bb, 0.f);
    xf[i * 64 + c] = y;
    if (last) xb[i * 64 + c] = f2bf(y);
  }
}

// ---------------- x1t / x2T builder: 4 channels per block ----------------
__global__ __launch_bounds__(256, 2) void k_build12(
    const u16* __restrict__ xbg, const unsigned char* __restrict__ eim,
    const float* __restrict__ m1W, const float* __restrict__ m1b,
    const float* __restrict__ m2W, const float* __restrict__ m2b,
    u16* __restrict__ x1tg, u16* __restrict__ x2tg, int cbase) {
  __shared__ u16 As[128 * 80];
  __shared__ u16 Bs[128 * 80];
  __shared__ u16 Cs[64 * 140];
  __shared__ unsigned char El[128 * 132];
  __shared__ float wsc[64];
  int b = blockIdx.x;  // grid 512 = 2(which) x 64 tiles x 4 channel-quads
  int cg = b & 3;
  int rest = b >> 2;
  int which = rest >> 6;
  int t6 = rest & 63;
  int rbase = (t6 >> 3) * 128, sbase = (t6 & 7) * 128;
  const float* W = which ? m2W : m1W;
  const float* bias = which ? m2b : m1b;
  u16* outg = which ? x2tg : x1tg;
  int t = threadIdx.x;
  {
    int row = t >> 1, half = t & 1;
    const u32* gB = (const u32*)(xbg + (sbase + row) * 64 + half * 32);
    u32* dstB = (u32*)&Bs[row * 80 + half * 32];
#pragma unroll
    for (int k = 0; k < 16; ++k) dstB[k] = gB[k];
    int ab = which ? sbase : rbase;
    int bb = which ? rbase : sbase;
    const u32* gE = (const u32*)(eim + (size_t)(ab + row) * 1024 + bb + half * 64);
    u32* dstE = (u32*)&El[row * 132 + half * 64];
#pragma unroll
    for (int k = 0; k < 16; ++k) dstE[k] = gE[k];
  }
  int lane = t & 63, w = t >> 6;
  int q = lane >> 4, r = lane & 15;
  int wr = w >> 1, wc = w & 1;
  for (int ci = 0; ci < 4; ++ci) {
    int cl = cg * 4 + ci;
    int c = cbase + cl;
    if (t < 64) wsc[t] = W[t * 64 + c];
    __syncthreads();
    {
      int row = t >> 1, half = t & 1;
      const u32* ga = (const u32*)(xbg + (rbase + row) * 64 + half * 32);
      u32* dstA = (u32*)&As[row * 80 + half * 32];
#pragma unroll
      for (int k = 0; k < 16; ++k) {
        u32 u = ga[k];
        float f0 = bf2f((u16)(u & 0xffffu)) * wsc[half * 32 + 2 * k];
        float f1 = bf2f((u16)(u >> 16)) * wsc[half * 32 + 2 * k + 1];
        dstA[k] = (u32)f2bf(f0) | ((u32)f2bf(f1) << 16);
      }
    }
    __syncthreads();
    f32x4 z4 = {0.f, 0.f, 0.f, 0.f};
    f32x4 acc[4][4];
#pragma unroll
    for (int mi = 0; mi < 4; ++mi)
#pragma unroll
      for (int ni = 0; ni < 4; ++ni) acc[mi][ni] = z4;
#pragma unroll
    for (int ks = 0; ks < 2; ++ks) {
      bf16x8 af[4], bfr[4];
#pragma unroll
      for (int mi = 0; mi < 4; ++mi)
        af[mi] = *(const bf16x8*)&As[(wr * 64 + mi * 16 + r) * 80 + ks * 32 + q * 8];
#pragma unroll
      for (int ni = 0; ni < 4; ++ni)
        bfr[ni] = *(const bf16x8*)&Bs[(wc * 64 + ni * 16 + r) * 80 + ks * 32 + q * 8];
#pragma unroll
      for (int mi = 0; mi < 4; ++mi)
#pragma unroll
        for (int ni = 0; ni < 4; ++ni) acc[mi][ni] = MFMA16(af[mi], bfr[ni], acc[mi][ni]);
    }
    float w64 = W[64 * 64 + c];
    float bsv = bias[c];
#pragma unroll
    for (int mi = 0; mi < 4; ++mi) {
#pragma unroll
      for (int ni = 0; ni < 4; ++ni) {
        int col = wc * 64 + ni * 16 + r;
#pragma unroll
        for (int tt = 0; tt < 4; ++tt) {
          int row2 = wr * 64 + mi * 16 + q * 4 + tt;
          float e = (float)(which ? El[col * 132 + row2] : El[row2 * 132 + col]);
          acc[mi][ni][tt] = fmaxf(acc[mi][ni][tt] + e * w64 + bsv, 0.f);
        }
      }
    }
    u16* outp = outg + (size_t)cl * 1048576;
#pragma unroll
    for (int p = 0; p < 2; ++p) {
      __syncthreads();
      if (wr == p) {
#pragma unroll
        for (int mi = 0; mi < 4; ++mi)
#pragma unroll
          for (int ni = 0; ni < 4; ++ni) {
            int col = wc * 64 + ni * 16 + r;
#pragma unroll
            for (int tt = 0; tt < 4; ++tt) {
              int lrow = mi * 16 + q * 4 + tt;
              Cs[lrow * 140 + col] = f2bf(acc[mi][ni][tt]);
            }
          }
      }
      __syncthreads();
      {
        int rl = t >> 4, ch = t & 15;
#pragma unroll
        for (int it = 0; it < 4; ++it) {
          int row = it * 16 + rl;
          uint4 v = *(const uint4*)&Cs[row * 140 + ch * 8];
          *(uint4*)(outp + (size_t)(rbase + p * 64 + row) * 1024 + sbase + ch * 8) = v;
        }
      }
    }
  }
}

// ---------------- batched prod GEMM (16 channels per launch) ----------------
// R11 version: XCD-aware block swizzle — all 64 tiles of one channel land on
// one XCD consecutively: per-XCD A+B = 4MB = L2 capacity.
__global__ __launch_bounds__(256, 4) void k_prodgemm(
    const u16* __restrict__ x1tg, const u16* __restrict__ x2tg,
    u16* __restrict__ prod, int cbase) {
  __shared__ u16 pool[17408];
  int b = blockIdx.x;  // grid 1024
  int cl = (b & 7) + ((b >> 9) << 3);   // channel: XCD x gets cl=x then cl=x+8
  int tile = (b >> 3) & 63;             // 64 tiles of that channel, in order
  int i0 = (tile >> 3) * 128, j0 = (tile & 7) * 128;
  const u16* Ap = x1tg + (size_t)cl * 1048576;
  const u16* Bp = x2tg + (size_t)cl * 1048576;
  u16* Pp = prod + (size_t)(cbase + cl) * 1048576;
  int t = threadIdx.x, lane = t & 63, w = t >> 6;
  int q = lane >> 4, r = lane & 15;
  int wr = w >> 1, wc = w & 1;
  int lrow = lane >> 3, lcol = (lane & 7) * 8;
  f32x4 z4 = {0.f, 0.f, 0.f, 0.f};
  f32x4 acc[4][4];
#pragma unroll
  for (int mi = 0; mi < 4; ++mi)
#pragma unroll
    for (int ni = 0; ni < 4; ++ni) acc[mi][ni] = z4;
  for (int kk = 0; kk < 1024; kk += 64) {
    __syncthreads();
#pragma unroll
    for (int s8 = 0; s8 < 4; ++s8) {
      int rowbase = w * 32 + s8 * 8;
      int grow = rowbase + lrow;
      __builtin_amdgcn_global_load_lds(
          (gas1)(Ap + (size_t)(i0 + grow) * 1024 + kk + lcol),
          (las3)&pool[rowbase * 64], 16, 0, 0);
      __builtin_amdgcn_global_load_lds(
          (gas1)(Bp + (size_t)(j0 + grow) * 1024 + kk + lcol),
          (las3)&pool[8192 + rowbase * 64], 16, 0, 0);
    }
    __syncthreads();
#pragma unroll
    for (int ks = 0; ks < 2; ++ks) {
      bf16x8 af[4], bfr[4];
#pragma unroll
      for (int mi = 0; mi < 4; ++mi)
        af[mi] = *(const bf16x8*)&pool[(wr * 64 + mi * 16 + r) * 64 + ks * 32 + q * 8];
#pragma unroll
      for (int ni = 0; ni < 4; ++ni)
        bfr[ni] = *(const bf16x8*)&pool[8192 + (wc * 64 + ni * 16 + r) * 64 + ks * 32 + q * 8];
#pragma unroll
      for (int mi = 0; mi < 4; ++mi)
#pragma unroll
        for (int ni = 0; ni < 4; ++ni) acc[mi][ni] = MFMA16(af[mi], bfr[ni], acc[mi][ni]);
    }
  }
  __syncthreads();
#pragma unroll
  for (int mi = 0; mi < 4; ++mi)
#pragma unroll
    for (int ni = 0; ni < 4; ++ni) {
      int col = wc * 64 + ni * 16 + r;
#pragma unroll
      for (int tt = 0; tt < 4; ++tt) {
        int row2 = wr * 64 + mi * 16 + q * 4 + tt;
        pool[row2 * 136 + col] = f2bf(acc[mi][ni][tt]);
      }
    }
  __syncthreads();
  {
    int rseg = t >> 4, cseg = t & 15;
#pragma unroll
    for (int it = 0; it < 8; ++it) {
      int row = it * 16 + rseg;
      uint4 v = *(const uint4*)&pool[row * 136 + cseg * 8];
      *(uint4*)(Pp + (size_t)(i0 + row) * 1024 + j0 + cseg * 8) = v;
    }
  }
}

// ---------------- T = [x_i*x_j | eim | prod] @ m3W + b3 (IN PLACE over prod) --
// R12 inner structure; R18: j-range split across 2 blocks (grid 2048,
// 8 chunks/block) to amortize the 1-block/CU scheduling tail.
__global__ __launch_bounds__(256, 3) void k_buildT(
    const u16* __restrict__ xbg, const unsigned char* __restrict__ eim,
    u16* PT, const float* __restrict__ m3W, const float* __restrict__ m3b,
    float* __restrict__ S, float* __restrict__ SS) {
  __shared__ u16 A[64 * 136];          // 17408 B: [j][k] k=0..63 xi*xj, 64..127 prod^T
  __shared__ u16 Wt[64 * 136];         // 17408 B
  __shared__ u16 scratch[64 * 66];     // 8448 B: PT chunk [p][j] (+pad)
  __shared__ __align__(16) u16 stg[64 * 72];  // 9216 B: output staging [c][j]
  __shared__ unsigned char eimrow[1024];
  __shared__ float xi[64];
  // total 53760 B -> 3 blocks/CU (161280 <= 163840)
  int bx = blockIdx.x;  // grid 2048 = 1024 i x 2 j-halves
  int i = bx >> 1, bj = bx & 1;
  int jbase = bj * 512;
  int t = threadIdx.x, lane = t & 63, w = t >> 6;
  int q = lane >> 4, r = lane & 15;
  {
    int zidx = i * 256 + t;  // both bj blocks zero same region: idempotent
    if (zidx < 65536) { S[zidx] = 0.f; SS[zidx] = 0.f; }
  }
  if (t < 64) xi[t] = bf2f(xbg[i * 64 + t]);
  ((u32*)eimrow)[t] = ((const u32*)(eim + (size_t)i * 1024))[t];
  {
    int row = t >> 1, half = t & 1;
    int rsrc = row < 64 ? row : row + 1;  // skip eim row 64
    const float4* gw = (const float4*)(m3W + rsrc * 64 + half * 32);
#pragma unroll
    for (int k = 0; k < 8; ++k) {
      float4 f = gw[k];
      Wt[(half * 32 + 4 * k + 0) * 136 + row] = f2bf(f.x);
      Wt[(half * 32 + 4 * k + 1) * 136 + row] = f2bf(f.y);
      Wt[(half * 32 + 4 * k + 2) * 136 + row] = f2bf(f.z);
      Wt[(half * 32 + 4 * k + 3) * 136 + row] = f2bf(f.w);
    }
  }
  float w64c[4], b3c[4];
#pragma unroll
  for (int ni = 0; ni < 4; ++ni) {
    int cc = ni * 16 + r;
    w64c[ni] = m3W[64 * 64 + cc];
    b3c[ni] = m3b[cc];
  }
  int p4 = t >> 2, q4 = t & 3;  // thread -> (plane/row, 16-elem quarter)
  uint4 pva, pvb, xva, xvb;     // prefetch registers: PT 32B, xb 32B
  {
    const uint4* gp = (const uint4*)(PT + (size_t)p4 * 1048576 + (size_t)i * 1024 + jbase + q4 * 16);
    pva = gp[0]; pvb = gp[1];
    const uint4* gx = (const uint4*)(xbg + (jbase + p4) * 64 + q4 * 16);
    xva = gx[0]; xvb = gx[1];
  }
  for (int jc8 = 0; jc8 < 8; ++jc8) {
    int j0 = jbase + jc8 * 64;
    // bar1: stg (prev chunk) filled & flushed; A/scratch free for reuse
    asm volatile("s_waitcnt lgkmcnt(0)" ::: "memory");
    __builtin_amdgcn_s_barrier();
    asm volatile("" ::: "memory");
    // phase A: stage current chunk from regs into LDS
    {
      u32* sw = (u32*)&scratch[p4 * 66 + q4 * 16];
      sw[0] = pva.x; sw[1] = pva.y; sw[2] = pva.z; sw[3] = pva.w;
      sw[4] = pvb.x; sw[5] = pvb.y; sw[6] = pvb.z; sw[7] = pvb.w;
      u32 xv[8] = {xva.x, xva.y, xva.z, xva.w, xvb.x, xvb.y, xvb.z, xvb.w};
      u32* dst = (u32*)&A[p4 * 136 + q4 * 16];
#pragma unroll
      for (int k = 0; k < 8; ++k) {
        u32 u = xv[k];
        float f0 = bf2f((u16)(u & 0xffffu)) * xi[q4 * 16 + 2 * k];
        float f1 = bf2f((u16)(u >> 16)) * xi[q4 * 16 + 2 * k + 1];
        dst[k] = (u32)f2bf(f0) | ((u32)f2bf(f1) << 16);
      }
    }
    // prefetch next chunk into regs (stays in flight across raw barriers).
    // jc8<7 guard: never reads the other block's column half.
    if (jc8 < 7) {
      const uint4* gp = (const uint4*)(PT + (size_t)p4 * 1048576 + (size_t)i * 1024 + (j0 + 64) + q4 * 16);
      pva = gp[0]; pvb = gp[1];
      const uint4* gx = (const uint4*)(xbg + (j0 + 64 + p4) * 64 + q4 * 16);
      xva = gx[0]; xvb = gx[1];
    }
    // overlapped global store of previous chunk from stg
    if (jc8 > 0) {
      int pl = t >> 3, off = (t & 7) * 8;
#pragma unroll
      for (int k = 0; k < 2; ++k) {
        int plane = k * 32 + pl;
        uint4 v = *(const uint4*)&stg[plane * 72 + off];
        *(uint4*)(PT + (size_t)plane * 1048576 + (size_t)i * 1024 + (j0 - 64) + off) = v;
      }
    }
    // bar2: scratch + A cols 0-63 visible
    asm volatile("s_waitcnt lgkmcnt(0)" ::: "memory");
    __builtin_amdgcn_s_barrier();
    asm volatile("" ::: "memory");
    // phase B: transpose scratch [p][j] -> A cols 64-127 [j][64+p]
#pragma unroll
    for (int jj2 = 0; jj2 < 8; ++jj2) {
      int jr = w * 16 + jj2 * 2;
      u32 two = *(const u32*)&scratch[lane * 66 + jr];
      A[jr * 136 + 64 + lane] = (u16)(two & 0xffffu);
      A[(jr + 1) * 136 + 64 + lane] = (u16)(two >> 16);
    }
    // bar3: A complete
    asm volatile("s_waitcnt lgkmcnt(0)" ::: "memory");
    __builtin_amdgcn_s_barrier();
    asm volatile("" ::: "memory");
    // phase C: MFMA
    f32x4 z4 = {0.f, 0.f, 0.f, 0.f};
    f32x4 acc[4];
#pragma unroll
    for (int ni = 0; ni < 4; ++ni) acc[ni] = z4;
#pragma unroll
    for (int ks = 0; ks < 4; ++ks) {
      bf16x8 af, bfr[4];
      af = *(const bf16x8*)&A[(w * 16 + r) * 136 + ks * 32 + q * 8];
#pragma unroll
      for (int ni = 0; ni < 4; ++ni)
        bfr[ni] = *(const bf16x8*)&Wt[(ni * 16 + r) * 136 + ks * 32 + q * 8];
#pragma unroll
      for (int ni = 0; ni < 4; ++ni) acc[ni] = MFMA16(af, bfr[ni], acc[ni]);
    }
#pragma unroll
    for (int tt = 0; tt < 4; ++tt) {
      int jj = w * 16 + q * 4 + tt;
      float ev = (float)eimrow[j0 + jj];
#pragma unroll
      for (int ni = 0; ni < 4; ++ni)
        acc[ni][tt] = acc[ni][tt] + ev * w64c[ni] + b3c[ni];
    }
    // phase D: acc -> stg [c][j], packed b64
#pragma unroll
    for (int ni = 0; ni < 4; ++ni) {
      int cc = ni * 16 + r;
      u32 lo = (u32)f2bf(acc[ni][0]) | ((u32)f2bf(acc[ni][1]) << 16);
      u32 hi = (u32)f2bf(acc[ni][2]) | ((u32)f2bf(acc[ni][3]) << 16);
      uint2 vv; vv.x = lo; vv.y = hi;
      *(uint2*)&stg[cc * 72 + w * 16 + q * 4] = vv;
    }
  }
  // epilogue: store this block's last chunk (cols jbase+448..jbase+511)
  asm volatile("s_waitcnt lgkmcnt(0)" ::: "memory");
  __builtin_amdgcn_s_barrier();
  asm volatile("" ::: "memory");
  {
    int pl = t >> 3, off = (t & 7) * 8;
#pragma unroll
    for (int k = 0; k < 2; ++k) {
      int plane = k * 32 + pl;
      uint4 v = *(const uint4*)&stg[plane * 72 + off];
      *(uint4*)(PT + (size_t)plane * 1048576 + (size_t)i * 1024 + (jbase + 448) + off) = v;
    }
  }
}

// ---------------- graph-norm stats, pass 1: coalesced partial sums ----------
__global__ void k_stats(const u16* __restrict__ Tg, float* __restrict__ S,
                        float* __restrict__ SS) {
  int b = blockIdx.x;  // grid 512 = 64 c x 8 i-chunks
  int c = b >> 3, ic = b & 7;
  int t = threadIdx.x;
  const u16* base = Tg + (size_t)c * 1048576 + (size_t)ic * 131072 + t * 4;
  float s0 = 0.f, s1 = 0.f, s2 = 0.f, s3 = 0.f;
  float q0 = 0.f, q1 = 0.f, q2 = 0.f, q3 = 0.f;
  for (int ii = 0; ii < 128; ++ii) {
    uint2 u = *(const uint2*)(base + (size_t)ii * 1024);
    float v0 = bf2f((u16)(u.x & 0xffffu)), v1 = bf2f((u16)(u.x >> 16));
    float v2 = bf2f((u16)(u.y & 0xffffu)), v3 = bf2f((u16)(u.y >> 16));
    s0 += v0; q0 += v0 * v0;
    s1 += v1; q1 += v1 * v1;
    s2 += v2; q2 += v2 * v2;
    s3 += v3; q3 += v3 * v3;
  }
  int base2 = c * 1024 + t * 4;
  atomicAdd(&S[base2 + 0], s0);
  atomicAdd(&S[base2 + 1], s1);
  atomicAdd(&S[base2 + 2], s2);
  atomicAdd(&S[base2 + 3], s3);
  atomicAdd(&SS[base2 + 0], q0);
  atomicAdd(&SS[base2 + 1], q1);
  atomicAdd(&SS[base2 + 2], q2);
  atomicAdd(&SS[base2 + 3], q3);
}

// ---------------- graph-norm stats, pass 2: finalize ----------
__global__ void k_statsfin(const float* __restrict__ S, const float* __restrict__ SS,
                           const float* __restrict__ gn3w, const float* __restrict__ gn3b,
                           const float* __restrict__ gn3a,
                           float* __restrict__ normA, float* __restrict__ normB) {
  int idx = blockIdx.x * 256 + threadIdx.x;  // grid 256 -> 65536 = j*64+c
  int c = idx & 63, j = idx >> 6;
  float sum = S[c * 1024 + j];
  float ssum = SS[c * 1024 + j];
  float m = sum * (1.f / 1024.f);
  float a = gn3a[c];
  float var = ssum * (1.f / 1024.f) - (2.f * a - a * a) * m * m;
  float sc = gn3w[c] * rsqrtf(fmaxf(var, 0.f) + 1e-5f);
  normA[idx] = sc;
  normB[idx] = gn3b[c] - sc * a * m;
}

// ---------------- gather + symmetric product + final dot ----------------
__global__ void k_final(const u16* __restrict__ Tg, const float* __restrict__ normA,
                        const float* __restrict__ normB, const int* __restrict__ pos,
                        const float* __restrict__ ldW, const float* __restrict__ ldb,
                        float* __restrict__ out) {
  int t = threadIdx.x, w = t >> 6, lane = t & 63;  // grid 2048 x 256, wave/pos
  int p = blockIdx.x * 4 + w;
  int i = pos[2 * p], j = pos[2 * p + 1];
  float t1 = bf2f(Tg[(size_t)lane * 1048576 + (size_t)i * 1024 + j]);
  float y1 = fmaxf(normA[j * 64 + lane] * t1 + normB[j * 64 + lane], 0.f);
  float t2 = bf2f(Tg[(size_t)lane * 1048576 + (size_t)j * 1024 + i]);
  float y2 = fmaxf(normA[i * 64 + lane] * t2 + normB[i * 64 + lane], 0.f);
  float z = y1 * y2 * ldW[lane];
#pragma unroll
  for (int off = 32; off > 0; off >>= 1) z += __shfl_down(z, off, 64);
  if (lane == 0) out[p] = z + ldb[0];
}

extern "C" void kernel_launch(void* const* d_in, const int* in_sizes, int n_in,
                              void* d_out, int out_size, void* d_ws, size_t ws_size,
                              hipStream_t stream) {
  const int* xids   = (const int*)d_in[0];
  const int* ei     = (const int*)d_in[1];
  const int* pos    = (const int*)d_in[2];
  const float* emb  = (const float*)d_in[3];
  const float* gW0  = (const float*)d_in[4];
  const float* gb0  = (const float*)d_in[5];
  const float* gnw0 = (const float*)d_in[6];
  const float* gnb0 = (const float*)d_in[7];
  const float* gna0 = (const float*)d_in[8];
  const float* gW1  = (const float*)d_in[9];
  const float* gb1  = (const float*)d_in[10];
  const float* gnw1 = (const float*)d_in[11];
  const float* gnb1 = (const float*)d_in[12];
  const float* gna1 = (const float*)d_in[13];
  const float* m1W  = (const float*)d_in[14];
  const float* m1b  = (const float*)d_in[15];
  const float* m2W  = (const float*)d_in[16];
  const float* m2b  = (const float*)d_in[17];
  const float* m3W  = (const float*)d_in[18];
  const float* m3b  = (const float*)d_in[19];
  const float* gn3w = (const float*)d_in[20];
  const float* gn3b = (const float*)d_in[21];
  const float* gn3a = (const float*)d_in[22];
  const float* ldW  = (const float*)d_in[23];
  const float* ldb  = (const float*)d_in[24];

  char* ws = (char*)d_ws;
  float* xf   = (float*)(ws + 0);
  float* h    = (float*)(ws + 262144);
  float* agg  = (float*)(ws + 524288);
  float* deg  = (float*)(ws + 786432);
  u16*   xb   = (u16*)(ws + 790528);
  unsigned char* eim = (unsigned char*)(ws + 921600);
  float* normA = (float*)(ws + 1970176);
  float* normB = (float*)(ws + 2232320);
  u16* x1tg = (u16*)(ws + 2494464);
  u16* x2tg = (u16*)(ws + 36048896);
  u16* prod = (u16*)(ws + 69603328);  // later overwritten in place by T
  float* Sp  = (float*)x1tg;          // stats partials overlay dead x1tg
  float* SSp = Sp + 65536;
  float* out = (float*)d_out;

  k_setup<<<1024, 256, 0, stream>>>(xids, emb, xf, deg, (u32*)eim);
  k_edges<<<64, 256, 0, stream>>>(ei, deg, eim);
  // GCN layer 0
  k_gemm_node<<<1024, 64, 0, stream>>>(xf, gW0, gb0, deg, h, agg);
  k_agg<<<4096, 256, 0, stream>>>(ei, deg, h, agg);
  k_gnorm<<<64, 256, 0, stream>>>(agg, gnw0, gnb0, gna0, xf, xb, 0);
  // GCN layer 1
  k_gemm_node<<<1024, 64, 0, stream>>>(xf, gW1, gb1, deg, h, agg);
  k_agg<<<4096, 256, 0, stream>>>(ei, deg, h, agg);
  k_gnorm<<<64, 256, 0, stream>>>(agg, gnw1, gnb1, gna1, xf, xb, 1);
  // pairwise maps + batched 1024^3 GEMM, 4 channel-groups of 16
  for (int g = 0; g < 4; ++g) {
    k_build12<<<512, 256, 0, stream>>>(xb, eim, m1W, m1b, m2W, m2b, x1tg, x2tg, g * 16);
    k_prodgemm<<<1024, 256, 0, stream>>>(x1tg, x2tg, prod, g * 16);
  }
  // T tensor (in place over prod, j-split grid) + stats + final
  k_buildT<<<2048, 256, 0, stream>>>(xb, eim, prod, m3W, m3b, Sp, SSp);
  k_stats<<<512, 256, 0, stream>>>(prod, Sp, SSp);
  k_statsfin<<<256, 256, 0, stream>>>(Sp, SSp, gn3w, gn3b, gn3a, normA, normB);
  k_final<<<2048, 256, 0, stream>>>(prod, normA, normB, pos, ldW, ldb, out);
}

// Round 8
// 502.479 us; speedup vs baseline: 1.2831x; 1.0058x over previous
//
#include <hip/hip_runtime.h>

// FWLNet pipeline; see R5-R19 notes.
//
// R19 (from R18 @505.4us, buildT 66.7us flat): R18's occupancy rose (23->26.5)
// but dur didn't move -> tail wasn't binding; the serialized phase-A staging
// compute between bar1 and bar2 is. Fix (extracted from R14's one good idea,
// proven absmax 0.015625 there): FOLD xi INTO Wt at prologue time
// (T[c] = sum_k xj[k] * (xi[k]*W[k][c])). Phase A's A-left becomes a raw
// 2x b128 register->LDS copy (was 8x b32 + ~90 VALU of bf2f/mul/f2bf per
// thread per chunk, 8x per block, unhideable). xi LDS array deleted.
// Alignment: A pitch 136 u16 = 272 B = 17x16 -> uint4 stores aligned; lane
// pairs (p,p+8) alias 2-way on b128 writes = free (m136). No barrier/
// layout/prefetch/grid changes vs R18.
//
// ws layout unchanged (~194.4 MB).

typedef unsigned short u16;
typedef unsigned int u32;

#define DI static __device__ __forceinline__

DI float bf2f(u16 u) { union { u32 i; float f; } v; v.i = ((u32)u) << 16; return v.f; }
DI u16 f2bf(float f) {
  union { float f; u32 i; } v; v.f = f;
  u32 u = v.i;
  return (u16)((u + 0x7fffu + ((u >> 16) & 1u)) >> 16);
}

typedef __bf16 bf16x8 __attribute__((ext_vector_type(8)));
typedef float f32x4 __attribute__((ext_vector_type(4)));

#define MFMA16(a, b, c) __builtin_amdgcn_mfma_f32_16x16x32_bf16((a), (b), (c), 0, 0, 0)

typedef const __attribute__((address_space(1))) u32* gas1;
typedef __attribute__((address_space(3))) u32* las3;

// ---------------- node pipeline ----------------

__global__ void k_setup(const int* __restrict__ xids, const float* __restrict__ emb,
                        float* __restrict__ xf, float* __restrict__ deg,
                        u32* __restrict__ eimu) {
  int g = blockIdx.x * 256 + threadIdx.x;  // grid 1024
  if (g < 262144) eimu[g] = 0u;
  if (g < 1024) deg[g] = 1.0f;  // self-loop
  if (g < 65536) {
    int i = g >> 6, d = g & 63;
    xf[g] = emb[xids[i] * 64 + d];
  }
}

__global__ void k_edges(const int* __restrict__ ei, float* __restrict__ deg,
                        unsigned char* __restrict__ eim) {
  int e = blockIdx.x * 256 + threadIdx.x;  // grid 64
  if (e < 16384) {
    int s = ei[e], d = ei[16384 + e];
    atomicAdd(&deg[d], 1.0f);
    eim[s * 1024 + d] = 1;
  }
}

__global__ void k_gemm_node(const float* __restrict__ xf, const float* __restrict__ W,
                            const float* __restrict__ gb, const float* __restrict__ deg,
                            float* __restrict__ h, float* __restrict__ agg) {
  __shared__ float xrow[64];
  int i = blockIdx.x, c = threadIdx.x;  // grid 1024 x 64
  xrow[c] = xf[i * 64 + c];
  __syncthreads();
  float s = 0.f;
#pragma unroll
  for (int d = 0; d < 64; ++d) s += xrow[d] * W[d * 64 + c];
  h[i * 64 + c] = s;
  agg[i * 64 + c] = s / deg[i] + gb[c];
}

__global__ void k_agg(const int* __restrict__ ei, const float* __restrict__ deg,
                      const float* __restrict__ h, float* __restrict__ agg) {
  int g = blockIdx.x * 256 + threadIdx.x;  // grid 4096 -> e x c
  int e = g >> 6, c = g & 63;
  int s = ei[e], d = ei[16384 + e];
  float nrm = rsqrtf(deg[s]) * rsqrtf(deg[d]);
  atomicAdd(&agg[d * 64 + c], nrm * h[s * 64 + c]);
}

__global__ void k_gnorm(const float* __restrict__ agg, const float* __restrict__ gw,
                        const float* __restrict__ gbb, const float* __restrict__ ga,
                        float* __restrict__ xf, u16* __restrict__ xb, int last) {
  int c = blockIdx.x, t = threadIdx.x;  // grid 64 x 256
  float s = 0.f, ss = 0.f;
  for (int i = t; i < 1024; i += 256) {
    float v = agg[i * 64 + c];
    s += v; ss += v * v;
  }
  __shared__ float Ls[256], Lss[256];
  Ls[t] = s; Lss[t] = ss;
  __syncthreads();
  for (int off = 128; off > 0; off >>= 1) {
    if (t < off) { Ls[t] += Ls[t + off]; Lss[t] += Lss[t + off]; }
    __syncthreads();
  }
  float m = Ls[0] * (1.f / 1024.f);
  float a = ga[c];
  float var = Lss[0] * (1.f / 1024.f) - (2.f * a - a * a) * m * m;
  float sc = gw[c] * rsqrtf(fmaxf(var, 0.f) + 1e-5f);
  float bb = gbb[c];
  for (int i = t; i < 1024; i += 256) {
    float v = agg[i * 64 + c];
    float y = fmaxf(sc * (v - a * m) + bb, 0.f);
    xf[i * 64 + c] = y;
    if (last) xb[i * 64 + c] = f2bf(y);
  }
}

// ---------------- x1t / x2T builder: 4 channels per block ----------------
__global__ __launch_bounds__(256, 2) void k_build12(
    const u16* __restrict__ xbg, const unsigned char* __restrict__ eim,
    const float* __restrict__ m1W, const float* __restrict__ m1b,
    const float* __restrict__ m2W, const float* __restrict__ m2b,
    u16* __restrict__ x1tg, u16* __restrict__ x2tg, int cbase) {
  __shared__ u16 As[128 * 80];
  __shared__ u16 Bs[128 * 80];
  __shared__ u16 Cs[64 * 140];
  __shared__ unsigned char El[128 * 132];
  __shared__ float wsc[64];
  int b = blockIdx.x;  // grid 512 = 2(which) x 64 tiles x 4 channel-quads
  int cg = b & 3;
  int rest = b >> 2;
  int which = rest >> 6;
  int t6 = rest & 63;
  int rbase = (t6 >> 3) * 128, sbase = (t6 & 7) * 128;
  const float* W = which ? m2W : m1W;
  const float* bias = which ? m2b : m1b;
  u16* outg = which ? x2tg : x1tg;
  int t = threadIdx.x;
  {
    int row = t >> 1, half = t & 1;
    const u32* gB = (const u32*)(xbg + (sbase + row) * 64 + half * 32);
    u32* dstB = (u32*)&Bs[row * 80 + half * 32];
#pragma unroll
    for (int k = 0; k < 16; ++k) dstB[k] = gB[k];
    int ab = which ? sbase : rbase;
    int bb = which ? rbase : sbase;
    const u32* gE = (const u32*)(eim + (size_t)(ab + row) * 1024 + bb + half * 64);
    u32* dstE = (u32*)&El[row * 132 + half * 64];
#pragma unroll
    for (int k = 0; k < 16; ++k) dstE[k] = gE[k];
  }
  int lane = t & 63, w = t >> 6;
  int q = lane >> 4, r = lane & 15;
  int wr = w >> 1, wc = w & 1;
  for (int ci = 0; ci < 4; ++ci) {
    int cl = cg * 4 + ci;
    int c = cbase + cl;
    if (t < 64) wsc[t] = W[t * 64 + c];
    __syncthreads();
    {
      int row = t >> 1, half = t & 1;
      const u32* ga = (const u32*)(xbg + (rbase + row) * 64 + half * 32);
      u32* dstA = (u32*)&As[row * 80 + half * 32];
#pragma unroll
      for (int k = 0; k < 16; ++k) {
        u32 u = ga[k];
        float f0 = bf2f((u16)(u & 0xffffu)) * wsc[half * 32 + 2 * k];
        float f1 = bf2f((u16)(u >> 16)) * wsc[half * 32 + 2 * k + 1];
        dstA[k] = (u32)f2bf(f0) | ((u32)f2bf(f1) << 16);
      }
    }
    __syncthreads();
    f32x4 z4 = {0.f, 0.f, 0.f, 0.f};
    f32x4 acc[4][4];
#pragma unroll
    for (int mi = 0; mi < 4; ++mi)
#pragma unroll
      for (int ni = 0; ni < 4; ++ni) acc[mi][ni] = z4;
#pragma unroll
    for (int ks = 0; ks < 2; ++ks) {
      bf16x8 af[4], bfr[4];
#pragma unroll
      for (int mi = 0; mi < 4; ++mi)
        af[mi] = *(const bf16x8*)&As[(wr * 64 + mi * 16 + r) * 80 + ks * 32 + q * 8];
#pragma unroll
      for (int ni = 0; ni < 4; ++ni)
        bfr[ni] = *(const bf16x8*)&Bs[(wc * 64 + ni * 16 + r) * 80 + ks * 32 + q * 8];
#pragma unroll
      for (int mi = 0; mi < 4; ++mi)
#pragma unroll
        for (int ni = 0; ni < 4; ++ni) acc[mi][ni] = MFMA16(af[mi], bfr[ni], acc[mi][ni]);
    }
    float w64 = W[64 * 64 + c];
    float bsv = bias[c];
#pragma unroll
    for (int mi = 0; mi < 4; ++mi) {
#pragma unroll
      for (int ni = 0; ni < 4; ++ni) {
        int col = wc * 64 + ni * 16 + r;
#pragma unroll
        for (int tt = 0; tt < 4; ++tt) {
          int row2 = wr * 64 + mi * 16 + q * 4 + tt;
          float e = (float)(which ? El[col * 132 + row2] : El[row2 * 132 + col]);
          acc[mi][ni][tt] = fmaxf(acc[mi][ni][tt] + e * w64 + bsv, 0.f);
        }
      }
    }
    u16* outp = outg + (size_t)cl * 1048576;
#pragma unroll
    for (int p = 0; p < 2; ++p) {
      __syncthreads();
      if (wr == p) {
#pragma unroll
        for (int mi = 0; mi < 4; ++mi)
#pragma unroll
          for (int ni = 0; ni < 4; ++ni) {
            int col = wc * 64 + ni * 16 + r;
#pragma unroll
            for (int tt = 0; tt < 4; ++tt) {
              int lrow = mi * 16 + q * 4 + tt;
              Cs[lrow * 140 + col] = f2bf(acc[mi][ni][tt]);
            }
          }
      }
      __syncthreads();
      {
        int rl = t >> 4, ch = t & 15;
#pragma unroll
        for (int it = 0; it < 4; ++it) {
          int row = it * 16 + rl;
          uint4 v = *(const uint4*)&Cs[row * 140 + ch * 8];
          *(uint4*)(outp + (size_t)(rbase + p * 64 + row) * 1024 + sbase + ch * 8) = v;
        }
      }
    }
  }
}

// ---------------- batched prod GEMM (16 channels per launch) ----------------
// R11 version: XCD-aware block swizzle — all 64 tiles of one channel land on
// one XCD consecutively: per-XCD A+B = 4MB = L2 capacity.
__global__ __launch_bounds__(256, 4) void k_prodgemm(
    const u16* __restrict__ x1tg, const u16* __restrict__ x2tg,
    u16* __restrict__ prod, int cbase) {
  __shared__ u16 pool[17408];
  int b = blockIdx.x;  // grid 1024
  int cl = (b & 7) + ((b >> 9) << 3);   // channel: XCD x gets cl=x then cl=x+8
  int tile = (b >> 3) & 63;             // 64 tiles of that channel, in order
  int i0 = (tile >> 3) * 128, j0 = (tile & 7) * 128;
  const u16* Ap = x1tg + (size_t)cl * 1048576;
  const u16* Bp = x2tg + (size_t)cl * 1048576;
  u16* Pp = prod + (size_t)(cbase + cl) * 1048576;
  int t = threadIdx.x, lane = t & 63, w = t >> 6;
  int q = lane >> 4, r = lane & 15;
  int wr = w >> 1, wc = w & 1;
  int lrow = lane >> 3, lcol = (lane & 7) * 8;
  f32x4 z4 = {0.f, 0.f, 0.f, 0.f};
  f32x4 acc[4][4];
#pragma unroll
  for (int mi = 0; mi < 4; ++mi)
#pragma unroll
    for (int ni = 0; ni < 4; ++ni) acc[mi][ni] = z4;
  for (int kk = 0; kk < 1024; kk += 64) {
    __syncthreads();
#pragma unroll
    for (int s8 = 0; s8 < 4; ++s8) {
      int rowbase = w * 32 + s8 * 8;
      int grow = rowbase + lrow;
      __builtin_amdgcn_global_load_lds(
          (gas1)(Ap + (size_t)(i0 + grow) * 1024 + kk + lcol),
          (las3)&pool[rowbase * 64], 16, 0, 0);
      __builtin_amdgcn_global_load_lds(
          (gas1)(Bp + (size_t)(j0 + grow) * 1024 + kk + lcol),
          (las3)&pool[8192 + rowbase * 64], 16, 0, 0);
    }
    __syncthreads();
#pragma unroll
    for (int ks = 0; ks < 2; ++ks) {
      bf16x8 af[4], bfr[4];
#pragma unroll
      for (int mi = 0; mi < 4; ++mi)
        af[mi] = *(const bf16x8*)&pool[(wr * 64 + mi * 16 + r) * 64 + ks * 32 + q * 8];
#pragma unroll
      for (int ni = 0; ni < 4; ++ni)
        bfr[ni] = *(const bf16x8*)&pool[8192 + (wc * 64 + ni * 16 + r) * 64 + ks * 32 + q * 8];
#pragma unroll
      for (int mi = 0; mi < 4; ++mi)
#pragma unroll
        for (int ni = 0; ni < 4; ++ni) acc[mi][ni] = MFMA16(af[mi], bfr[ni], acc[mi][ni]);
    }
  }
  __syncthreads();
#pragma unroll
  for (int mi = 0; mi < 4; ++mi)
#pragma unroll
    for (int ni = 0; ni < 4; ++ni) {
      int col = wc * 64 + ni * 16 + r;
#pragma unroll
      for (int tt = 0; tt < 4; ++tt) {
        int row2 = wr * 64 + mi * 16 + q * 4 + tt;
        pool[row2 * 136 + col] = f2bf(acc[mi][ni][tt]);
      }
    }
  __syncthreads();
  {
    int rseg = t >> 4, cseg = t & 15;
#pragma unroll
    for (int it = 0; it < 8; ++it) {
      int row = it * 16 + rseg;
      uint4 v = *(const uint4*)&pool[row * 136 + cseg * 8];
      *(uint4*)(Pp + (size_t)(i0 + row) * 1024 + j0 + cseg * 8) = v;
    }
  }
}

// ---------------- T = [x_i*x_j | eim | prod] @ m3W + b3 (IN PLACE over prod) --
// R12 inner structure; R18 j-split grid (2048, 8 chunks/block); R19: xi folded
// into Wt rows k<64 at prologue -> phase-A A-left is a raw 2x b128 copy.
__global__ __launch_bounds__(256, 3) void k_buildT(
    const u16* __restrict__ xbg, const unsigned char* __restrict__ eim,
    u16* PT, const float* __restrict__ m3W, const float* __restrict__ m3b,
    float* __restrict__ S, float* __restrict__ SS) {
  __shared__ __align__(16) u16 A[64 * 136];   // 17408 B: [j][k] k<64 raw xj, k>=64 prod^T
  __shared__ u16 Wt[64 * 136];                // 17408 B: [c][k], rows k<64 pre-scaled by xi[k]
  __shared__ u16 scratch[64 * 66];            // 8448 B: PT chunk [p][j] (+pad)
  __shared__ __align__(16) u16 stg[64 * 72];  // 9216 B: output staging [c][j]
  __shared__ unsigned char eimrow[1024];
  // total 53504 B -> 3 blocks/CU (160512 <= 163840)
  int bx = blockIdx.x;  // grid 2048 = 1024 i x 2 j-halves
  int i = bx >> 1, bj = bx & 1;
  int jbase = bj * 512;
  int t = threadIdx.x, lane = t & 63, w = t >> 6;
  int q = lane >> 4, r = lane & 15;
  {
    int zidx = i * 256 + t;  // both bj blocks zero same region: idempotent
    if (zidx < 65536) { S[zidx] = 0.f; SS[zidx] = 0.f; }
  }
  ((u32*)eimrow)[t] = ((const u32*)(eim + (size_t)i * 1024))[t];
  {
    int row = t >> 1, half = t & 1;
    int rsrc = row < 64 ? row : row + 1;  // skip eim row 64
    // R19: fold xi into Wt rows k<64 (T[c] = sum_k xj[k] * (xi[k]*W[k][c]))
    float xsc = (row < 64) ? bf2f(xbg[i * 64 + row]) : 1.f;
    const float4* gw = (const float4*)(m3W + rsrc * 64 + half * 32);
#pragma unroll
    for (int k = 0; k < 8; ++k) {
      float4 f = gw[k];
      Wt[(half * 32 + 4 * k + 0) * 136 + row] = f2bf(f.x * xsc);
      Wt[(half * 32 + 4 * k + 1) * 136 + row] = f2bf(f.y * xsc);
      Wt[(half * 32 + 4 * k + 2) * 136 + row] = f2bf(f.z * xsc);
      Wt[(half * 32 + 4 * k + 3) * 136 + row] = f2bf(f.w * xsc);
    }
  }
  float w64c[4], b3c[4];
#pragma unroll
  for (int ni = 0; ni < 4; ++ni) {
    int cc = ni * 16 + r;
    w64c[ni] = m3W[64 * 64 + cc];
    b3c[ni] = m3b[cc];
  }
  int p4 = t >> 2, q4 = t & 3;  // thread -> (plane/row, 16-elem quarter)
  uint4 pva, pvb, xva, xvb;     // prefetch registers: PT 32B, xb 32B
  {
    const uint4* gp = (const uint4*)(PT + (size_t)p4 * 1048576 + (size_t)i * 1024 + jbase + q4 * 16);
    pva = gp[0]; pvb = gp[1];
    const uint4* gx = (const uint4*)(xbg + (jbase + p4) * 64 + q4 * 16);
    xva = gx[0]; xvb = gx[1];
  }
  for (int jc8 = 0; jc8 < 8; ++jc8) {
    int j0 = jbase + jc8 * 64;
    // bar1: stg (prev chunk) filled & flushed; A/scratch free for reuse
    asm volatile("s_waitcnt lgkmcnt(0)" ::: "memory");
    __builtin_amdgcn_s_barrier();
    asm volatile("" ::: "memory");
    // phase A: stage current chunk from regs into LDS.
    // R19: A-left is raw xj (xi folded into Wt) -> plain b128 copies.
    {
      u32* sw = (u32*)&scratch[p4 * 66 + q4 * 16];
      sw[0] = pva.x; sw[1] = pva.y; sw[2] = pva.z; sw[3] = pva.w;
      sw[4] = pvb.x; sw[5] = pvb.y; sw[6] = pvb.z; sw[7] = pvb.w;
      *(uint4*)&A[p4 * 136 + q4 * 16] = xva;
      *(uint4*)&A[p4 * 136 + q4 * 16 + 8] = xvb;
    }
    // prefetch next chunk into regs (stays in flight across raw barriers).
    // jc8<7 guard: never reads the other block's column half.
    if (jc8 < 7) {
      const uint4* gp = (const uint4*)(PT + (size_t)p4 * 1048576 + (size_t)i * 1024 + (j0 + 64) + q4 * 16);
      pva = gp[0]; pvb = gp[1];
      const uint4* gx = (const uint4*)(xbg + (j0 + 64 + p4) * 64 + q4 * 16);
      xva = gx[0]; xvb = gx[1];
    }
    // overlapped global store of previous chunk from stg
    if (jc8 > 0) {
      int pl = t >> 3, off = (t & 7) * 8;
#pragma unroll
      for (int k = 0; k < 2; ++k) {
        int plane = k * 32 + pl;
        uint4 v = *(const uint4*)&stg[plane * 72 + off];
        *(uint4*)(PT + (size_t)plane * 1048576 + (size_t)i * 1024 + (j0 - 64) + off) = v;
      }
    }
    // bar2: scratch + A cols 0-63 visible
    asm volatile("s_waitcnt lgkmcnt(0)" ::: "memory");
    __builtin_amdgcn_s_barrier();
    asm volatile("" ::: "memory");
    // phase B: transpose scratch [p][j] -> A cols 64-127 [j][64+p]
#pragma unroll
    for (int jj2 = 0; jj2 < 8; ++jj2) {
      int jr = w * 16 + jj2 * 2;
      u32 two = *(const u32*)&scratch[lane * 66 + jr];
      A[jr * 136 + 64 + lane] = (u16)(two & 0xffffu);
      A[(jr + 1) * 136 + 64 + lane] = (u16)(two >> 16);
    }
    // bar3: A complete
    asm volatile("s_waitcnt lgkmcnt(0)" ::: "memory");
    __builtin_amdgcn_s_barrier();
    asm volatile("" ::: "memory");
    // phase C: MFMA
    f32x4 z4 = {0.f, 0.f, 0.f, 0.f};
    f32x4 acc[4];
#pragma unroll
    for (int ni = 0; ni < 4; ++ni) acc[ni] = z4;
#pragma unroll
    for (int ks = 0; ks < 4; ++ks) {
      bf16x8 af, bfr[4];
      af = *(const bf16x8*)&A[(w * 16 + r) * 136 + ks * 32 + q * 8];
#pragma unroll
      for (int ni = 0; ni < 4; ++ni)
        bfr[ni] = *(const bf16x8*)&Wt[(ni * 16 + r) * 136 + ks * 32 + q * 8];
#pragma unroll
      for (int ni = 0; ni < 4; ++ni) acc[ni] = MFMA16(af, bfr[ni], acc[ni]);
    }
#pragma unroll
    for (int tt = 0; tt < 4; ++tt) {
      int jj = w * 16 + q * 4 + tt;
      float ev = (float)eimrow[j0 + jj];
#pragma unroll
      for (int ni = 0; ni < 4; ++ni)
        acc[ni][tt] = acc[ni][tt] + ev * w64c[ni] + b3c[ni];
    }
    // phase D: acc -> stg [c][j], packed b64
#pragma unroll
    for (int ni = 0; ni < 4; ++ni) {
      int cc = ni * 16 + r;
      u32 lo = (u32)f2bf(acc[ni][0]) | ((u32)f2bf(acc[ni][1]) << 16);
      u32 hi = (u32)f2bf(acc[ni][2]) | ((u32)f2bf(acc[ni][3]) << 16);
      uint2 vv; vv.x = lo; vv.y = hi;
      *(uint2*)&stg[cc * 72 + w * 16 + q * 4] = vv;
    }
  }
  // epilogue: store this block's last chunk (cols jbase+448..jbase+511)
  asm volatile("s_waitcnt lgkmcnt(0)" ::: "memory");
  __builtin_amdgcn_s_barrier();
  asm volatile("" ::: "memory");
  {
    int pl = t >> 3, off = (t & 7) * 8;
#pragma unroll
    for (int k = 0; k < 2; ++k) {
      int plane = k * 32 + pl;
      uint4 v = *(const uint4*)&stg[plane * 72 + off];
      *(uint4*)(PT + (size_t)plane * 1048576 + (size_t)i * 1024 + (jbase + 448) + off) = v;
    }
  }
}

// ---------------- graph-norm stats, pass 1: coalesced partial sums ----------
__global__ void k_stats(const u16* __restrict__ Tg, float* __restrict__ S,
                        float* __restrict__ SS) {
  int b = blockIdx.x;  // grid 512 = 64 c x 8 i-chunks
  int c = b >> 3, ic = b & 7;
  int t = threadIdx.x;
  const u16* base = Tg + (size_t)c * 1048576 + (size_t)ic * 131072 + t * 4;
  float s0 = 0.f, s1 = 0.f, s2 = 0.f, s3 = 0.f;
  float q0 = 0.f, q1 = 0.f, q2 = 0.f, q3 = 0.f;
  for (int ii = 0; ii < 128; ++ii) {
    uint2 u = *(const uint2*)(base + (size_t)ii * 1024);
    float v0 = bf2f((u16)(u.x & 0xffffu)), v1 = bf2f((u16)(u.x >> 16));
    float v2 = bf2f((u16)(u.y & 0xffffu)), v3 = bf2f((u16)(u.y >> 16));
    s0 += v0; q0 += v0 * v0;
    s1 += v1; q1 += v1 * v1;
    s2 += v2; q2 += v2 * v2;
    s3 += v3; q3 += v3 * v3;
  }
  int base2 = c * 1024 + t * 4;
  atomicAdd(&S[base2 + 0], s0);
  atomicAdd(&S[base2 + 1], s1);
  atomicAdd(&S[base2 + 2], s2);
  atomicAdd(&S[base2 + 3], s3);
  atomicAdd(&SS[base2 + 0], q0);
  atomicAdd(&SS[base2 + 1], q1);
  atomicAdd(&SS[base2 + 2], q2);
  atomicAdd(&SS[base2 + 3], q3);
}

// ---------------- graph-norm stats, pass 2: finalize ----------
__global__ void k_statsfin(const float* __restrict__ S, const float* __restrict__ SS,
                           const float* __restrict__ gn3w, const float* __restrict__ gn3b,
                           const float* __restrict__ gn3a,
                           float* __restrict__ normA, float* __restrict__ normB) {
  int idx = blockIdx.x * 256 + threadIdx.x;  // grid 256 -> 65536 = j*64+c
  int c = idx & 63, j = idx >> 6;
  float sum = S[c * 1024 + j];
  float ssum = SS[c * 1024 + j];
  float m = sum * (1.f / 1024.f);
  float a = gn3a[c];
  float var = ssum * (1.f / 1024.f) - (2.f * a - a * a) * m * m;
  float sc = gn3w[c] * rsqrtf(fmaxf(var, 0.f) + 1e-5f);
  normA[idx] = sc;
  normB[idx] = gn3b[c] - sc * a * m;
}

// ---------------- gather + symmetric product + final dot ----------------
__global__ void k_final(const u16* __restrict__ Tg, const float* __restrict__ normA,
                        const float* __restrict__ normB, const int* __restrict__ pos,
                        const float* __restrict__ ldW, const float* __restrict__ ldb,
                        float* __restrict__ out) {
  int t = threadIdx.x, w = t >> 6, lane = t & 63;  // grid 2048 x 256, wave/pos
  int p = blockIdx.x * 4 + w;
  int i = pos[2 * p], j = pos[2 * p + 1];
  float t1 = bf2f(Tg[(size_t)lane * 1048576 + (size_t)i * 1024 + j]);
  float y1 = fmaxf(normA[j * 64 + lane] * t1 + normB[j * 64 + lane], 0.f);
  float t2 = bf2f(Tg[(size_t)lane * 1048576 + (size_t)j * 1024 + i]);
  float y2 = fmaxf(normA[i * 64 + lane] * t2 + normB[i * 64 + lane], 0.f);
  float z = y1 * y2 * ldW[lane];
#pragma unroll
  for (int off = 32; off > 0; off >>= 1) z += __shfl_down(z, off, 64);
  if (lane == 0) out[p] = z + ldb[0];
}

extern "C" void kernel_launch(void* const* d_in, const int* in_sizes, int n_in,
                              void* d_out, int out_size, void* d_ws, size_t ws_size,
                              hipStream_t stream) {
  const int* xids   = (const int*)d_in[0];
  const int* ei     = (const int*)d_in[1];
  const int* pos    = (const int*)d_in[2];
  const float* emb  = (const float*)d_in[3];
  const float* gW0  = (const float*)d_in[4];
  const float* gb0  = (const float*)d_in[5];
  const float* gnw0 = (const float*)d_in[6];
  const float* gnb0 = (const float*)d_in[7];
  const float* gna0 = (const float*)d_in[8];
  const float* gW1  = (const float*)d_in[9];
  const float* gb1  = (const float*)d_in[10];
  const float* gnw1 = (const float*)d_in[11];
  const float* gnb1 = (const float*)d_in[12];
  const float* gna1 = (const float*)d_in[13];
  const float* m1W  = (const float*)d_in[14];
  const float* m1b  = (const float*)d_in[15];
  const float* m2W  = (const float*)d_in[16];
  const float* m2b  = (const float*)d_in[17];
  const float* m3W  = (const float*)d_in[18];
  const float* m3b  = (const float*)d_in[19];
  const float* gn3w = (const float*)d_in[20];
  const float* gn3b = (const float*)d_in[21];
  const float* gn3a = (const float*)d_in[22];
  const float* ldW  = (const float*)d_in[23];
  const float* ldb  = (const float*)d_in[24];

  char* ws = (char*)d_ws;
  float* xf   = (float*)(ws + 0);
  float* h    = (float*)(ws + 262144);
  float* agg  = (float*)(ws + 524288);
  float* deg  = (float*)(ws + 786432);
  u16*   xb   = (u16*)(ws + 790528);
  unsigned char* eim = (unsigned char*)(ws + 921600);
  float* normA = (float*)(ws + 1970176);
  float* normB = (float*)(ws + 2232320);
  u16* x1tg = (u16*)(ws + 2494464);
  u16* x2tg = (u16*)(ws + 36048896);
  u16* prod = (u16*)(ws + 69603328);  // later overwritten in place by T
  float* Sp  = (float*)x1tg;          // stats partials overlay dead x1tg
  float* SSp = Sp + 65536;
  float* out = (float*)d_out;

  k_setup<<<1024, 256, 0, stream>>>(xids, emb, xf, deg, (u32*)eim);
  k_edges<<<64, 256, 0, stream>>>(ei, deg, eim);
  // GCN layer 0
  k_gemm_node<<<1024, 64, 0, stream>>>(xf, gW0, gb0, deg, h, agg);
  k_agg<<<4096, 256, 0, stream>>>(ei, deg, h, agg);
  k_gnorm<<<64, 256, 0, stream>>>(agg, gnw0, gnb0, gna0, xf, xb, 0);
  // GCN layer 1
  k_gemm_node<<<1024, 64, 0, stream>>>(xf, gW1, gb1, deg, h, agg);
  k_agg<<<4096, 256, 0, stream>>>(ei, deg, h, agg);
  k_gnorm<<<64, 256, 0, stream>>>(agg, gnw1, gnb1, gna1, xf, xb, 1);
  // pairwise maps + batched 1024^3 GEMM, 4 channel-groups of 16
  for (int g = 0; g < 4; ++g) {
    k_build12<<<512, 256, 0, stream>>>(xb, eim, m1W, m1b, m2W, m2b, x1tg, x2tg, g * 16);
    k_prodgemm<<<1024, 256, 0, stream>>>(x1tg, x2tg, prod, g * 16);
  }
  // T tensor (in place over prod, j-split grid) + stats + final
  k_buildT<<<2048, 256, 0, stream>>>(xb, eim, prod, m3W, m3b, Sp, SSp);
  k_stats<<<512, 256, 0, stream>>>(prod, Sp, SSp);
  k_statsfin<<<256, 256, 0, stream>>>(Sp, SSp, gn3w, gn3b, gn3a, normA, normB);
  k_final<<<2048, 256, 0, stream>>>(prod, normA, normB, pos, ldW, ldb, out);
}

// Round 9
// 498.577 us; speedup vs baseline: 1.2931x; 1.0078x over previous
//
#include <hip/hip_runtime.h>

// FWLNet pipeline; see R5-R20 notes.
//
// R20 (from R19 @502.5us): buildT fold landed as predicted (66.7->62.0,
// VALU 33.8->22.6). Next-largest consumer: k_prodgemm 4x~40us at the m97
// drain-stall ceiling (sync;STAGE;sync-full-drain;MFMA = ~250cy exposed L2
// latency per K-tile, MfmaUtil ~35%). R20: T3-minimum 2-phase dbuf INSIDE
// R11's shape: BK 64->32, A/B K-tiles double-buffered (4x4096 u16 = 32KB,
// fits existing 34KB pool; 4 blocks/CU and grid 1024 unchanged); per tile:
// issue STAGE(kt+1) first, then vmcnt(4) => tile kt landed, kt+1's 4 loads
// in flight under MFMA. Ledger: <=8 outstanding/wave; buf[kt&1] rewritten
// only in iter kt+1 after iter-kt's closing lgkm-barrier; pitch-32 frag
// reads bank-even ((4r+q)%8, 8 lanes/group); K-slice order unchanged ->
// bitwise-identical output. Everything else identical to R19.
//
// ws layout unchanged (~194.4 MB).

typedef unsigned short u16;
typedef unsigned int u32;

#define DI static __device__ __forceinline__

DI float bf2f(u16 u) { union { u32 i; float f; } v; v.i = ((u32)u) << 16; return v.f; }
DI u16 f2bf(float f) {
  union { float f; u32 i; } v; v.f = f;
  u32 u = v.i;
  return (u16)((u + 0x7fffu + ((u >> 16) & 1u)) >> 16);
}

typedef __bf16 bf16x8 __attribute__((ext_vector_type(8)));
typedef float f32x4 __attribute__((ext_vector_type(4)));

#define MFMA16(a, b, c) __builtin_amdgcn_mfma_f32_16x16x32_bf16((a), (b), (c), 0, 0, 0)

typedef const __attribute__((address_space(1))) u32* gas1;
typedef __attribute__((address_space(3))) u32* las3;

// ---------------- node pipeline ----------------

__global__ void k_setup(const int* __restrict__ xids, const float* __restrict__ emb,
                        float* __restrict__ xf, float* __restrict__ deg,
                        u32* __restrict__ eimu) {
  int g = blockIdx.x * 256 + threadIdx.x;  // grid 1024
  if (g < 262144) eimu[g] = 0u;
  if (g < 1024) deg[g] = 1.0f;  // self-loop
  if (g < 65536) {
    int i = g >> 6, d = g & 63;
    xf[g] = emb[xids[i] * 64 + d];
  }
}

__global__ void k_edges(const int* __restrict__ ei, float* __restrict__ deg,
                        unsigned char* __restrict__ eim) {
  int e = blockIdx.x * 256 + threadIdx.x;  // grid 64
  if (e < 16384) {
    int s = ei[e], d = ei[16384 + e];
    atomicAdd(&deg[d], 1.0f);
    eim[s * 1024 + d] = 1;
  }
}

__global__ void k_gemm_node(const float* __restrict__ xf, const float* __restrict__ W,
                            const float* __restrict__ gb, const float* __restrict__ deg,
                            float* __restrict__ h, float* __restrict__ agg) {
  __shared__ float xrow[64];
  int i = blockIdx.x, c = threadIdx.x;  // grid 1024 x 64
  xrow[c] = xf[i * 64 + c];
  __syncthreads();
  float s = 0.f;
#pragma unroll
  for (int d = 0; d < 64; ++d) s += xrow[d] * W[d * 64 + c];
  h[i * 64 + c] = s;
  agg[i * 64 + c] = s / deg[i] + gb[c];
}

__global__ void k_agg(const int* __restrict__ ei, const float* __restrict__ deg,
                      const float* __restrict__ h, float* __restrict__ agg) {
  int g = blockIdx.x * 256 + threadIdx.x;  // grid 4096 -> e x c
  int e = g >> 6, c = g & 63;
  int s = ei[e], d = ei[16384 + e];
  float nrm = rsqrtf(deg[s]) * rsqrtf(deg[d]);
  atomicAdd(&agg[d * 64 + c], nrm * h[s * 64 + c]);
}

__global__ void k_gnorm(const float* __restrict__ agg, const float* __restrict__ gw,
                        const float* __restrict__ gbb, const float* __restrict__ ga,
                        float* __restrict__ xf, u16* __restrict__ xb, int last) {
  int c = blockIdx.x, t = threadIdx.x;  // grid 64 x 256
  float s = 0.f, ss = 0.f;
  for (int i = t; i < 1024; i += 256) {
    float v = agg[i * 64 + c];
    s += v; ss += v * v;
  }
  __shared__ float Ls[256], Lss[256];
  Ls[t] = s; Lss[t] = ss;
  __syncthreads();
  for (int off = 128; off > 0; off >>= 1) {
    if (t < off) { Ls[t] += Ls[t + off]; Lss[t] += Lss[t + off]; }
    __syncthreads();
  }
  float m = Ls[0] * (1.f / 1024.f);
  float a = ga[c];
  float var = Lss[0] * (1.f / 1024.f) - (2.f * a - a * a) * m * m;
  float sc = gw[c] * rsqrtf(fmaxf(var, 0.f) + 1e-5f);
  float bb = gbb[c];
  for (int i = t; i < 1024; i += 256) {
    float v = agg[i * 64 + c];
    float y = fmaxf(sc * (v - a * m) + bb, 0.f);
    xf[i * 64 + c] = y;
    if (last) xb[i * 64 + c] = f2bf(y);
  }
}

// ---------------- x1t / x2T builder: 4 channels per block ----------------
__global__ __launch_bounds__(256, 2) void k_build12(
    const u16* __restrict__ xbg, const unsigned char* __restrict__ eim,
    const float* __restrict__ m1W, const float* __restrict__ m1b,
    const float* __restrict__ m2W, const float* __restrict__ m2b,
    u16* __restrict__ x1tg, u16* __restrict__ x2tg, int cbase) {
  __shared__ u16 As[128 * 80];
  __shared__ u16 Bs[128 * 80];
  __shared__ u16 Cs[64 * 140];
  __shared__ unsigned char El[128 * 132];
  __shared__ float wsc[64];
  int b = blockIdx.x;  // grid 512 = 2(which) x 64 tiles x 4 channel-quads
  int cg = b & 3;
  int rest = b >> 2;
  int which = rest >> 6;
  int t6 = rest & 63;
  int rbase = (t6 >> 3) * 128, sbase = (t6 & 7) * 128;
  const float* W = which ? m2W : m1W;
  const float* bias = which ? m2b : m1b;
  u16* outg = which ? x2tg : x1tg;
  int t = threadIdx.x;
  {
    int row = t >> 1, half = t & 1;
    const u32* gB = (const u32*)(xbg + (sbase + row) * 64 + half * 32);
    u32* dstB = (u32*)&Bs[row * 80 + half * 32];
#pragma unroll
    for (int k = 0; k < 16; ++k) dstB[k] = gB[k];
    int ab = which ? sbase : rbase;
    int bb = which ? rbase : sbase;
    const u32* gE = (const u32*)(eim + (size_t)(ab + row) * 1024 + bb + half * 64);
    u32* dstE = (u32*)&El[row * 132 + half * 64];
#pragma unroll
    for (int k = 0; k < 16; ++k) dstE[k] = gE[k];
  }
  int lane = t & 63, w = t >> 6;
  int q = lane >> 4, r = lane & 15;
  int wr = w >> 1, wc = w & 1;
  for (int ci = 0; ci < 4; ++ci) {
    int cl = cg * 4 + ci;
    int c = cbase + cl;
    if (t < 64) wsc[t] = W[t * 64 + c];
    __syncthreads();
    {
      int row = t >> 1, half = t & 1;
      const u32* ga = (const u32*)(xbg + (rbase + row) * 64 + half * 32);
      u32* dstA = (u32*)&As[row * 80 + half * 32];
#pragma unroll
      for (int k = 0; k < 16; ++k) {
        u32 u = ga[k];
        float f0 = bf2f((u16)(u & 0xffffu)) * wsc[half * 32 + 2 * k];
        float f1 = bf2f((u16)(u >> 16)) * wsc[half * 32 + 2 * k + 1];
        dstA[k] = (u32)f2bf(f0) | ((u32)f2bf(f1) << 16);
      }
    }
    __syncthreads();
    f32x4 z4 = {0.f, 0.f, 0.f, 0.f};
    f32x4 acc[4][4];
#pragma unroll
    for (int mi = 0; mi < 4; ++mi)
#pragma unroll
      for (int ni = 0; ni < 4; ++ni) acc[mi][ni] = z4;
#pragma unroll
    for (int ks = 0; ks < 2; ++ks) {
      bf16x8 af[4], bfr[4];
#pragma unroll
      for (int mi = 0; mi < 4; ++mi)
        af[mi] = *(const bf16x8*)&As[(wr * 64 + mi * 16 + r) * 80 + ks * 32 + q * 8];
#pragma unroll
      for (int ni = 0; ni < 4; ++ni)
        bfr[ni] = *(const bf16x8*)&Bs[(wc * 64 + ni * 16 + r) * 80 + ks * 32 + q * 8];
#pragma unroll
      for (int mi = 0; mi < 4; ++mi)
#pragma unroll
        for (int ni = 0; ni < 4; ++ni) acc[mi][ni] = MFMA16(af[mi], bfr[ni], acc[mi][ni]);
    }
    float w64 = W[64 * 64 + c];
    float bsv = bias[c];
#pragma unroll
    for (int mi = 0; mi < 4; ++mi) {
#pragma unroll
      for (int ni = 0; ni < 4; ++ni) {
        int col = wc * 64 + ni * 16 + r;
#pragma unroll
        for (int tt = 0; tt < 4; ++tt) {
          int row2 = wr * 64 + mi * 16 + q * 4 + tt;
          float e = (float)(which ? El[col * 132 + row2] : El[row2 * 132 + col]);
          acc[mi][ni][tt] = fmaxf(acc[mi][ni][tt] + e * w64 + bsv, 0.f);
        }
      }
    }
    u16* outp = outg + (size_t)cl * 1048576;
#pragma unroll
    for (int p = 0; p < 2; ++p) {
      __syncthreads();
      if (wr == p) {
#pragma unroll
        for (int mi = 0; mi < 4; ++mi)
#pragma unroll
          for (int ni = 0; ni < 4; ++ni) {
            int col = wc * 64 + ni * 16 + r;
#pragma unroll
            for (int tt = 0; tt < 4; ++tt) {
              int lrow = mi * 16 + q * 4 + tt;
              Cs[lrow * 140 + col] = f2bf(acc[mi][ni][tt]);
            }
          }
      }
      __syncthreads();
      {
        int rl = t >> 4, ch = t & 15;
#pragma unroll
        for (int it = 0; it < 4; ++it) {
          int row = it * 16 + rl;
          uint4 v = *(const uint4*)&Cs[row * 140 + ch * 8];
          *(uint4*)(outp + (size_t)(rbase + p * 64 + row) * 1024 + sbase + ch * 8) = v;
        }
      }
    }
  }
}

// ---------------- batched prod GEMM (16 channels per launch) ----------------
// R11 shape (128^2 tile, 4 waves, 4 blocks/CU, grid 1024, XCD channel
// swizzle) + R20: BK=32 double-buffered K-tiles with counted vmcnt.
// Per tile kt: issue STAGE(kt+1) into parity^1, then vmcnt(4) (tile kt's 4
// loads done; kt+1's 4 in flight under MFMA), barrier, 8x ds_read_b128
// (pitch-32, bank-even) + 16 MFMA, lgkm(0)+barrier (protects buf rewrite).
__global__ __launch_bounds__(256, 4) void k_prodgemm(
    const u16* __restrict__ x1tg, const u16* __restrict__ x2tg,
    u16* __restrict__ prod, int cbase) {
  __shared__ u16 pool[17408];  // A0@0 B0@4096 A1@8192 B1@12288 (dbuf), writeback overlays
  int b = blockIdx.x;  // grid 1024
  int cl = (b & 7) + ((b >> 9) << 3);   // channel: XCD x gets cl=x then cl=x+8
  int tile = (b >> 3) & 63;             // 64 tiles of that channel, in order
  int i0 = (tile >> 3) * 128, j0 = (tile & 7) * 128;
  const u16* Ap = x1tg + (size_t)cl * 1048576;
  const u16* Bp = x2tg + (size_t)cl * 1048576;
  u16* Pp = prod + (size_t)(cbase + cl) * 1048576;
  int t = threadIdx.x, lane = t & 63, w = t >> 6;
  int q = lane >> 4, r = lane & 15;
  int wr = w >> 1, wc = w & 1;
  int srow = lane >> 2, scol = (lane & 3) * 8;  // stage mapping (16B/lane)

#define PSTAGE(KT)                                                          \
  {                                                                         \
    int pb_ = (KT) & 1;                                                     \
    int kk_ = (KT) * 32;                                                    \
    _Pragma("unroll")                                                       \
    for (int s = 0; s < 2; ++s) {                                           \
      int rowb = w * 32 + s * 16;                                           \
      __builtin_amdgcn_global_load_lds(                                     \
          (gas1)(Ap + (size_t)(i0 + rowb + srow) * 1024 + kk_ + scol),      \
          (las3)(pool + pb_ * 8192 + rowb * 32), 16, 0, 0);                 \
      __builtin_amdgcn_global_load_lds(                                     \
          (gas1)(Bp + (size_t)(j0 + rowb + srow) * 1024 + kk_ + scol),      \
          (las3)(pool + pb_ * 8192 + 4096 + rowb * 32), 16, 0, 0);          \
    }                                                                       \
  }

  f32x4 z4 = {0.f, 0.f, 0.f, 0.f};
  f32x4 acc[4][4];
#pragma unroll
  for (int mi = 0; mi < 4; ++mi)
#pragma unroll
    for (int ni = 0; ni < 4; ++ni) acc[mi][ni] = z4;

  PSTAGE(0);  // prologue: tile 0 -> parity 0; no wait (first iter's vmcnt covers)
#pragma unroll 2
  for (int kt = 0; kt < 32; ++kt) {
    int pb = kt & 1;
    if (kt < 31) {
      PSTAGE(kt + 1);  // into parity pb^1 (its previous readers finished at
                       // iter kt-1's closing barrier)
      asm volatile("s_waitcnt vmcnt(4)" ::: "memory");  // tile kt landed
    } else {
      asm volatile("s_waitcnt vmcnt(0)" ::: "memory");
    }
    __builtin_amdgcn_s_barrier();  // all waves' tile-kt DMA visible
    asm volatile("" ::: "memory");
    {
      bf16x8 af[4], bfr[4];
#pragma unroll
      for (int mi = 0; mi < 4; ++mi)
        af[mi] = *(const bf16x8*)&pool[pb * 8192 + (wr * 64 + mi * 16 + r) * 32 + q * 8];
#pragma unroll
      for (int ni = 0; ni < 4; ++ni)
        bfr[ni] = *(const bf16x8*)&pool[pb * 8192 + 4096 + (wc * 64 + ni * 16 + r) * 32 + q * 8];
#pragma unroll
      for (int mi = 0; mi < 4; ++mi)
#pragma unroll
        for (int ni = 0; ni < 4; ++ni) acc[mi][ni] = MFMA16(af[mi], bfr[ni], acc[mi][ni]);
    }
    asm volatile("s_waitcnt lgkmcnt(0)" ::: "memory");
    __builtin_amdgcn_s_barrier();  // frag reads done -> buf[pb] safe to rewrite
    asm volatile("" ::: "memory");
  }
#undef PSTAGE

  __syncthreads();
#pragma unroll
  for (int mi = 0; mi < 4; ++mi)
#pragma unroll
    for (int ni = 0; ni < 4; ++ni) {
      int col = wc * 64 + ni * 16 + r;
#pragma unroll
      for (int tt = 0; tt < 4; ++tt) {
        int row2 = wr * 64 + mi * 16 + q * 4 + tt;
        pool[row2 * 136 + col] = f2bf(acc[mi][ni][tt]);
      }
    }
  __syncthreads();
  {
    int rseg = t >> 4, cseg = t & 15;
#pragma unroll
    for (int it = 0; it < 8; ++it) {
      int row = it * 16 + rseg;
      uint4 v = *(const uint4*)&pool[row * 136 + cseg * 8];
      *(uint4*)(Pp + (size_t)(i0 + row) * 1024 + j0 + cseg * 8) = v;
    }
  }
}

// ---------------- T = [x_i*x_j | eim | prod] @ m3W + b3 (IN PLACE over prod) --
// R12 inner structure; R18 j-split grid (2048, 8 chunks/block); R19: xi folded
// into Wt rows k<64 at prologue -> phase-A A-left is a raw 2x b128 copy.
__global__ __launch_bounds__(256, 3) void k_buildT(
    const u16* __restrict__ xbg, const unsigned char* __restrict__ eim,
    u16* PT, const float* __restrict__ m3W, const float* __restrict__ m3b,
    float* __restrict__ S, float* __restrict__ SS) {
  __shared__ __align__(16) u16 A[64 * 136];   // 17408 B: [j][k] k<64 raw xj, k>=64 prod^T
  __shared__ u16 Wt[64 * 136];                // 17408 B: [c][k], rows k<64 pre-scaled by xi[k]
  __shared__ u16 scratch[64 * 66];            // 8448 B: PT chunk [p][j] (+pad)
  __shared__ __align__(16) u16 stg[64 * 72];  // 9216 B: output staging [c][j]
  __shared__ unsigned char eimrow[1024];
  // total 53504 B -> 3 blocks/CU (160512 <= 163840)
  int bx = blockIdx.x;  // grid 2048 = 1024 i x 2 j-halves
  int i = bx >> 1, bj = bx & 1;
  int jbase = bj * 512;
  int t = threadIdx.x, lane = t & 63, w = t >> 6;
  int q = lane >> 4, r = lane & 15;
  {
    int zidx = i * 256 + t;  // both bj blocks zero same region: idempotent
    if (zidx < 65536) { S[zidx] = 0.f; SS[zidx] = 0.f; }
  }
  ((u32*)eimrow)[t] = ((const u32*)(eim + (size_t)i * 1024))[t];
  {
    int row = t >> 1, half = t & 1;
    int rsrc = row < 64 ? row : row + 1;  // skip eim row 64
    // R19: fold xi into Wt rows k<64 (T[c] = sum_k xj[k] * (xi[k]*W[k][c]))
    float xsc = (row < 64) ? bf2f(xbg[i * 64 + row]) : 1.f;
    const float4* gw = (const float4*)(m3W + rsrc * 64 + half * 32);
#pragma unroll
    for (int k = 0; k < 8; ++k) {
      float4 f = gw[k];
      Wt[(half * 32 + 4 * k + 0) * 136 + row] = f2bf(f.x * xsc);
      Wt[(half * 32 + 4 * k + 1) * 136 + row] = f2bf(f.y * xsc);
      Wt[(half * 32 + 4 * k + 2) * 136 + row] = f2bf(f.z * xsc);
      Wt[(half * 32 + 4 * k + 3) * 136 + row] = f2bf(f.w * xsc);
    }
  }
  float w64c[4], b3c[4];
#pragma unroll
  for (int ni = 0; ni < 4; ++ni) {
    int cc = ni * 16 + r;
    w64c[ni] = m3W[64 * 64 + cc];
    b3c[ni] = m3b[cc];
  }
  int p4 = t >> 2, q4 = t & 3;  // thread -> (plane/row, 16-elem quarter)
  uint4 pva, pvb, xva, xvb;     // prefetch registers: PT 32B, xb 32B
  {
    const uint4* gp = (const uint4*)(PT + (size_t)p4 * 1048576 + (size_t)i * 1024 + jbase + q4 * 16);
    pva = gp[0]; pvb = gp[1];
    const uint4* gx = (const uint4*)(xbg + (jbase + p4) * 64 + q4 * 16);
    xva = gx[0]; xvb = gx[1];
  }
  for (int jc8 = 0; jc8 < 8; ++jc8) {
    int j0 = jbase + jc8 * 64;
    // bar1: stg (prev chunk) filled & flushed; A/scratch free for reuse
    asm volatile("s_waitcnt lgkmcnt(0)" ::: "memory");
    __builtin_amdgcn_s_barrier();
    asm volatile("" ::: "memory");
    // phase A: stage current chunk from regs into LDS.
    // R19: A-left is raw xj (xi folded into Wt) -> plain b128 copies.
    {
      u32* sw = (u32*)&scratch[p4 * 66 + q4 * 16];
      sw[0] = pva.x; sw[1] = pva.y; sw[2] = pva.z; sw[3] = pva.w;
      sw[4] = pvb.x; sw[5] = pvb.y; sw[6] = pvb.z; sw[7] = pvb.w;
      *(uint4*)&A[p4 * 136 + q4 * 16] = xva;
      *(uint4*)&A[p4 * 136 + q4 * 16 + 8] = xvb;
    }
    // prefetch next chunk into regs (stays in flight across raw barriers).
    // jc8<7 guard: never reads the other block's column half.
    if (jc8 < 7) {
      const uint4* gp = (const uint4*)(PT + (size_t)p4 * 1048576 + (size_t)i * 1024 + (j0 + 64) + q4 * 16);
      pva = gp[0]; pvb = gp[1];
      const uint4* gx = (const uint4*)(xbg + (j0 + 64 + p4) * 64 + q4 * 16);
      xva = gx[0]; xvb = gx[1];
    }
    // overlapped global store of previous chunk from stg
    if (jc8 > 0) {
      int pl = t >> 3, off = (t & 7) * 8;
#pragma unroll
      for (int k = 0; k < 2; ++k) {
        int plane = k * 32 + pl;
        uint4 v = *(const uint4*)&stg[plane * 72 + off];
        *(uint4*)(PT + (size_t)plane * 1048576 + (size_t)i * 1024 + (j0 - 64) + off) = v;
      }
    }
    // bar2: scratch + A cols 0-63 visible
    asm volatile("s_waitcnt lgkmcnt(0)" ::: "memory");
    __builtin_amdgcn_s_barrier();
    asm volatile("" ::: "memory");
    // phase B: transpose scratch [p][j] -> A cols 64-127 [j][64+p]
#pragma unroll
    for (int jj2 = 0; jj2 < 8; ++jj2) {
      int jr = w * 16 + jj2 * 2;
      u32 two = *(const u32*)&scratch[lane * 66 + jr];
      A[jr * 136 + 64 + lane] = (u16)(two & 0xffffu);
      A[(jr + 1) * 136 + 64 + lane] = (u16)(two >> 16);
    }
    // bar3: A complete
    asm volatile("s_waitcnt lgkmcnt(0)" ::: "memory");
    __builtin_amdgcn_s_barrier();
    asm volatile("" ::: "memory");
    // phase C: MFMA
    f32x4 z4 = {0.f, 0.f, 0.f, 0.f};
    f32x4 acc[4];
#pragma unroll
    for (int ni = 0; ni < 4; ++ni) acc[ni] = z4;
#pragma unroll
    for (int ks = 0; ks < 4; ++ks) {
      bf16x8 af, bfr[4];
      af = *(const bf16x8*)&A[(w * 16 + r) * 136 + ks * 32 + q * 8];
#pragma unroll
      for (int ni = 0; ni < 4; ++ni)
        bfr[ni] = *(const bf16x8*)&Wt[(ni * 16 + r) * 136 + ks * 32 + q * 8];
#pragma unroll
      for (int ni = 0; ni < 4; ++ni) acc[ni] = MFMA16(af, bfr[ni], acc[ni]);
    }
#pragma unroll
    for (int tt = 0; tt < 4; ++tt) {
      int jj = w * 16 + q * 4 + tt;
      float ev = (float)eimrow[j0 + jj];
#pragma unroll
      for (int ni = 0; ni < 4; ++ni)
        acc[ni][tt] = acc[ni][tt] + ev * w64c[ni] + b3c[ni];
    }
    // phase D: acc -> stg [c][j], packed b64
#pragma unroll
    for (int ni = 0; ni < 4; ++ni) {
      int cc = ni * 16 + r;
      u32 lo = (u32)f2bf(acc[ni][0]) | ((u32)f2bf(acc[ni][1]) << 16);
      u32 hi = (u32)f2bf(acc[ni][2]) | ((u32)f2bf(acc[ni][3]) << 16);
      uint2 vv; vv.x = lo; vv.y = hi;
      *(uint2*)&stg[cc * 72 + w * 16 + q * 4] = vv;
    }
  }
  // epilogue: store this block's last chunk (cols jbase+448..jbase+511)
  asm volatile("s_waitcnt lgkmcnt(0)" ::: "memory");
  __builtin_amdgcn_s_barrier();
  asm volatile("" ::: "memory");
  {
    int pl = t >> 3, off = (t & 7) * 8;
#pragma unroll
    for (int k = 0; k < 2; ++k) {
      int plane = k * 32 + pl;
      uint4 v = *(const uint4*)&stg[plane * 72 + off];
      *(uint4*)(PT + (size_t)plane * 1048576 + (size_t)i * 1024 + (jbase + 448) + off) = v;
    }
  }
}

// ---------------- graph-norm stats, pass 1: coalesced partial sums ----------
__global__ void k_stats(const u16* __restrict__ Tg, float* __restrict__ S,
                        float* __restrict__ SS) {
  int b = blockIdx.x;  // grid 512 = 64 c x 8 i-chunks
  int c = b >> 3, ic = b & 7;
  int t = threadIdx.x;
  const u16* base = Tg + (size_t)c * 1048576 + (size_t)ic * 131072 + t * 4;
  float s0 = 0.f, s1 = 0.f, s2 = 0.f, s3 = 0.f;
  float q0 = 0.f, q1 = 0.f, q2 = 0.f, q3 = 0.f;
  for (int ii = 0; ii < 128; ++ii) {
    uint2 u = *(const uint2*)(base + (size_t)ii * 1024);
    float v0 = bf2f((u16)(u.x & 0xffffu)), v1 = bf2f((u16)(u.x >> 16));
    float v2 = bf2f((u16)(u.y & 0xffffu)), v3 = bf2f((u16)(u.y >> 16));
    s0 += v0; q0 += v0 * v0;
    s1 += v1; q1 += v1 * v1;
    s2 += v2; q2 += v2 * v2;
    s3 += v3; q3 += v3 * v3;
  }
  int base2 = c * 1024 + t * 4;
  atomicAdd(&S[base2 + 0], s0);
  atomicAdd(&S[base2 + 1], s1);
  atomicAdd(&S[base2 + 2], s2);
  atomicAdd(&S[base2 + 3], s3);
  atomicAdd(&SS[base2 + 0], q0);
  atomicAdd(&SS[base2 + 1], q1);
  atomicAdd(&SS[base2 + 2], q2);
  atomicAdd(&SS[base2 + 3], q3);
}

// ---------------- graph-norm stats, pass 2: finalize ----------
__global__ void k_statsfin(const float* __restrict__ S, const float* __restrict__ SS,
                           const float* __restrict__ gn3w, const float* __restrict__ gn3b,
                           const float* __restrict__ gn3a,
                           float* __restrict__ normA, float* __restrict__ normB) {
  int idx = blockIdx.x * 256 + threadIdx.x;  // grid 256 -> 65536 = j*64+c
  int c = idx & 63, j = idx >> 6;
  float sum = S[c * 1024 + j];
  float ssum = SS[c * 1024 + j];
  float m = sum * (1.f / 1024.f);
  float a = gn3a[c];
  float var = ssum * (1.f / 1024.f) - (2.f * a - a * a) * m * m;
  float sc = gn3w[c] * rsqrtf(fmaxf(var, 0.f) + 1e-5f);
  normA[idx] = sc;
  normB[idx] = gn3b[c] - sc * a * m;
}

// ---------------- gather + symmetric product + final dot ----------------
__global__ void k_final(const u16* __restrict__ Tg, const float* __restrict__ normA,
                        const float* __restrict__ normB, const int* __restrict__ pos,
                        const float* __restrict__ ldW, const float* __restrict__ ldb,
                        float* __restrict__ out) {
  int t = threadIdx.x, w = t >> 6, lane = t & 63;  // grid 2048 x 256, wave/pos
  int p = blockIdx.x * 4 + w;
  int i = pos[2 * p], j = pos[2 * p + 1];
  float t1 = bf2f(Tg[(size_t)lane * 1048576 + (size_t)i * 1024 + j]);
  float y1 = fmaxf(normA[j * 64 + lane] * t1 + normB[j * 64 + lane], 0.f);
  float t2 = bf2f(Tg[(size_t)lane * 1048576 + (size_t)j * 1024 + i]);
  float y2 = fmaxf(normA[i * 64 + lane] * t2 + normB[i * 64 + lane], 0.f);
  float z = y1 * y2 * ldW[lane];
#pragma unroll
  for (int off = 32; off > 0; off >>= 1) z += __shfl_down(z, off, 64);
  if (lane == 0) out[p] = z + ldb[0];
}

extern "C" void kernel_launch(void* const* d_in, const int* in_sizes, int n_in,
                              void* d_out, int out_size, void* d_ws, size_t ws_size,
                              hipStream_t stream) {
  const int* xids   = (const int*)d_in[0];
  const int* ei     = (const int*)d_in[1];
  const int* pos    = (const int*)d_in[2];
  const float* emb  = (const float*)d_in[3];
  const float* gW0  = (const float*)d_in[4];
  const float* gb0  = (const float*)d_in[5];
  const float* gnw0 = (const float*)d_in[6];
  const float* gnb0 = (const float*)d_in[7];
  const float* gna0 = (const float*)d_in[8];
  const float* gW1  = (const float*)d_in[9];
  const float* gb1  = (const float*)d_in[10];
  const float* gnw1 = (const float*)d_in[11];
  const float* gnb1 = (const float*)d_in[12];
  const float* gna1 = (const float*)d_in[13];
  const float* m1W  = (const float*)d_in[14];
  const float* m1b  = (const float*)d_in[15];
  const float* m2W  = (const float*)d_in[16];
  const float* m2b  = (const float*)d_in[17];
  const float* m3W  = (const float*)d_in[18];
  const float* m3b  = (const float*)d_in[19];
  const float* gn3w = (const float*)d_in[20];
  const float* gn3b = (const float*)d_in[21];
  const float* gn3a = (const float*)d_in[22];
  const float* ldW  = (const float*)d_in[23];
  const float* ldb  = (const float*)d_in[24];

  char* ws = (char*)d_ws;
  float* xf   = (float*)(ws + 0);
  float* h    = (float*)(ws + 262144);
  float* agg  = (float*)(ws + 524288);
  float* deg  = (float*)(ws + 786432);
  u16*   xb   = (u16*)(ws + 790528);
  unsigned char* eim = (unsigned char*)(ws + 921600);
  float* normA = (float*)(ws + 1970176);
  float* normB = (float*)(ws + 2232320);
  u16* x1tg = (u16*)(ws + 2494464);
  u16* x2tg = (u16*)(ws + 36048896);
  u16* prod = (u16*)(ws + 69603328);  // later overwritten in place by T
  float* Sp  = (float*)x1tg;          // stats partials overlay dead x1tg
  float* SSp = Sp + 65536;
  float* out = (float*)d_out;

  k_setup<<<1024, 256, 0, stream>>>(xids, emb, xf, deg, (u32*)eim);
  k_edges<<<64, 256, 0, stream>>>(ei, deg, eim);
  // GCN layer 0
  k_gemm_node<<<1024, 64, 0, stream>>>(xf, gW0, gb0, deg, h, agg);
  k_agg<<<4096, 256, 0, stream>>>(ei, deg, h, agg);
  k_gnorm<<<64, 256, 0, stream>>>(agg, gnw0, gnb0, gna0, xf, xb, 0);
  // GCN layer 1
  k_gemm_node<<<1024, 64, 0, stream>>>(xf, gW1, gb1, deg, h, agg);
  k_agg<<<4096, 256, 0, stream>>>(ei, deg, h, agg);
  k_gnorm<<<64, 256, 0, stream>>>(agg, gnw1, gnb1, gna1, xf, xb, 1);
  // pairwise maps + batched 1024^3 GEMM, 4 channel-groups of 16
  for (int g = 0; g < 4; ++g) {
    k_build12<<<512, 256, 0, stream>>>(xb, eim, m1W, m1b, m2W, m2b, x1tg, x2tg, g * 16);
    k_prodgemm<<<1024, 256, 0, stream>>>(x1tg, x2tg, prod, g * 16);
  }
  // T tensor (in place over prod, j-split grid) + stats + final
  k_buildT<<<2048, 256, 0, stream>>>(xb, eim, prod, m3W, m3b, Sp, SSp);
  k_stats<<<512, 256, 0, stream>>>(prod, Sp, SSp);
  k_statsfin<<<256, 256, 0, stream>>>(Sp, SSp, gn3w, gn3b, gn3a, normA, normB);
  k_final<<<2048, 256, 0, stream>>>(prod, normA, normB, pos, ldW, ldb, out);
}